// Round 1
// baseline (8123.010 us; speedup 1.0000x reference)
//
#include <hip/hip_runtime.h>
#include <hip/hip_bf16.h>

// Dims (fixed by the problem)
#define BB 32
#define SS 160
#define KK 44
#define EE 300
#define HH 256
#define VV 32000
#define G3 768      // 3*H
#define EHP 576     // 556 padded to mult of 32
#define EP  320     // 300 padded to mult of 32
#define NSEQ 5120   // B*S
#define NROW 10240  // 2 key sets * NSEQ
#define NKEY 20480  // 2 dirs * NROW

typedef unsigned short u16;
typedef __attribute__((ext_vector_type(8))) short bf16x8;
typedef __attribute__((ext_vector_type(4))) float f32x4;

static __device__ __forceinline__ u16 f2bf(float f) {
  union { float f; unsigned u; } x; x.f = f;
  unsigned u = x.u;
  unsigned r = (u + 0x7fffu + ((u >> 16) & 1u)) >> 16;
  return (u16)r;
}
static __device__ __forceinline__ float bf2f(u16 v) {
  union { unsigned u; float f; } x; x.u = ((unsigned)v) << 16;
  return x.f;
}

// fp32 (rows,K) -> bf16 (rows,ldp) with zero pad cols K..ldp
__global__ void cvt_pad(const float* __restrict__ src, u16* __restrict__ dst,
                        int rows, int K, int ldp) {
  int idx = blockIdx.x * blockDim.x + threadIdx.x;
  int tot = rows * ldp;
  if (idx >= tot) return;
  int c = idx % ldp; int r = idx / ldp;
  float v = (c < K) ? src[(size_t)r * K + c] : 0.f;
  dst[idx] = f2bf(v);
}

// C = A @ B^T + bias. A:(M,lda) bf16 row-major, B:(N,ldb) bf16 row-major.
// Rows < halfM use B0/bias0, else B1/bias1 (tiles never straddle halfM).
// Output fp32 to C (if Cbf==null) else bf16 to Cbf. M%16==0,N%16==0,K%32==0.
__global__ void gemm_bt(const u16* __restrict__ A, const u16* __restrict__ B0,
                        const u16* __restrict__ B1, int halfM,
                        float* __restrict__ C, u16* __restrict__ Cbf,
                        const float* __restrict__ bias0, const float* __restrict__ bias1,
                        int M, int N, int K, int lda, int ldb, int ldc) {
  int gid = blockIdx.x * blockDim.x + threadIdx.x;
  int wid = gid >> 6, lane = gid & 63;
  int ntiles = N >> 4;
  int total = (M >> 4) * ntiles;
  if (wid >= total) return;
  int tm = wid / ntiles, tn = wid - tm * ntiles;
  int rbase = tm << 4;
  const u16* Bm = (rbase < halfM) ? B0 : B1;
  const float* bias = (rbase < halfM) ? bias0 : bias1;
  int m = lane & 15, quad = lane >> 4;
  const u16* ap = A + (size_t)(rbase + m) * lda + quad * 8;
  const u16* bp = Bm + (size_t)((tn << 4) + m) * ldb + quad * 8;
  f32x4 acc = {0.f, 0.f, 0.f, 0.f};
  for (int k = 0; k < K; k += 32) {
    bf16x8 av = *(const bf16x8*)(ap + k);
    bf16x8 bv = *(const bf16x8*)(bp + k);
    acc = __builtin_amdgcn_mfma_f32_16x16x32_bf16(av, bv, acc, 0, 0, 0);
  }
  int col = (tn << 4) + m;
  float bv = bias ? bias[col] : 0.f;
  int orow = rbase + quad * 4;
  if (Cbf) {
    for (int i = 0; i < 4; ++i)
      Cbf[(size_t)(orow + i) * ldc + col] = f2bf(acc[i] + bv);
  } else {
    for (int i = 0; i < 4; ++i)
      C[(size_t)(orow + i) * ldc + col] = acc[i] + bv;
  }
}

// Key GRU elementwise update. Rows: [0,5120) fwd keys_c, [5120,10240) fwd keys_r,
// [10240,15360) bwd keys_c, [15360,20480) bwd keys_r. gh already includes bhh.
__global__ void key_update(const float* __restrict__ gh, const u16* __restrict__ TF,
                           const u16* __restrict__ TB, const int* __restrict__ keys_c,
                           const int* __restrict__ keys_r, float* __restrict__ h,
                           u16* __restrict__ hbf, int t) {
  int idx = blockIdx.x * blockDim.x + threadIdx.x;
  if (idx >= NKEY * HH) return;
  int j = idx & 255, row = idx >> 8;
  int bwd = row >= NROW;
  int sn = row - (bwd ? NROW : 0);
  int isR = sn >= NSEQ;
  int seq = sn - (isR ? NSEQ : 0);
  int tt = bwd ? (KK - 1 - t) : t;
  int tok = (isR ? keys_r : keys_c)[seq * KK + tt];
  const u16* gi = (bwd ? TB : TF) + (size_t)tok * G3;
  const float* ghr = gh + (size_t)row * G3;
  float ir = bf2f(gi[j]), iz = bf2f(gi[j + 256]), inn = bf2f(gi[j + 512]);
  float hr = ghr[j], hz = ghr[j + 256], hn = ghr[j + 512];
  float r = 1.f / (1.f + expf(-(ir + hr)));
  float z = 1.f / (1.f + expf(-(iz + hz)));
  float n = tanhf(inn + r * hn);
  float hnew = (1.f - z) * n + z * h[idx];
  h[idx] = hnew;
  hbf[idx] = f2bf(hnew);
}

// Build concat inputs for the main GRU, bf16 padded:
// xe rows [0,5120): x1e = [emb[x1], hf+hb(keys_c)]; rows [5120,10240): x2e.
__global__ void build_xe(const float* __restrict__ emb, const int* __restrict__ x1,
                         const int* __restrict__ x2, const float* __restrict__ hk,
                         u16* __restrict__ xe) {
  int idx = blockIdx.x * blockDim.x + threadIdx.x;
  if (idx >= NROW * EHP) return;
  int c = idx % EHP; int rr = idx / EHP;
  int isX2 = rr >= NSEQ;
  int seq = rr - (isX2 ? NSEQ : 0);
  float v;
  if (c < EE) {
    int tok = (isX2 ? x2 : x1)[seq];
    v = emb[(size_t)tok * EE + c];
  } else if (c < EE + HH) {
    int j = c - EE;
    int frow = (isX2 ? NSEQ : 0) + seq;
    v = hk[(size_t)frow * HH + j] + hk[(size_t)(NROW + frow) * HH + j];
  } else {
    v = 0.f;
  }
  xe[idx] = f2bf(v);
}

// Main GRU update. 128 rows: q=row>>5: 0=x1 fwd,1=x2 fwd,2=x1 bwd,3=x2 bwd.
__global__ void main_update(const float* __restrict__ gh, const float* __restrict__ Gf,
                            const float* __restrict__ Gb, float* __restrict__ h,
                            u16* __restrict__ hbf, float* __restrict__ sc,
                            u16* __restrict__ scbf, int t) {
  int idx = blockIdx.x * blockDim.x + threadIdx.x;
  if (idx >= 128 * HH) return;
  int j = idx & 255, row = idx >> 8;
  int q = row >> 5, bb = row & 31;
  int bwd = q >> 1;
  int isX2 = q & 1;
  int s = bwd ? (SS - 1 - t) : t;
  const float* G = bwd ? Gb : Gf;
  const float* gi = G + (size_t)(isX2 * NSEQ + bb * SS + s) * G3;
  const float* ghr = gh + (size_t)row * G3;
  float ir = gi[j], iz = gi[j + 256], inn = gi[j + 512];
  float hr = ghr[j], hz = ghr[j + 256], hn = ghr[j + 512];
  float r = 1.f / (1.f + expf(-(ir + hr)));
  float z = 1.f / (1.f + expf(-(iz + hz)));
  float n = tanhf(inn + r * hn);
  float hnew = (1.f - z) * n + z * h[idx];
  h[idx] = hnew;
  hbf[idx] = f2bf(hnew);
  if (!isX2) {
    size_t o = (size_t)(bb * SS + s) * 512 + (bwd ? 256 : 0) + j;
    sc[o] = hnew;
    scbf[o] = f2bf(hnew);
  }
}

// r = concat(r1f, r1b): finals of x2 fwd (rows 32..63) and x2 bwd (rows 96..127)
__global__ void extract_r(const float* __restrict__ h, float* __restrict__ r) {
  int idx = blockIdx.x * blockDim.x + threadIdx.x;
  if (idx >= BB * 512) return;
  int bb = idx >> 9, j = idx & 511;
  int row = (j < 256) ? (32 + bb) : (96 + bb);
  r[idx] = h[row * HH + (j & 255)];
}

// energies[b][s] = dot(a[b*S+s], r[b]); one wave per (b,s)
__global__ void energies_k(const float* __restrict__ a, const float* __restrict__ r,
                           float* __restrict__ e) {
  int gid = blockIdx.x * blockDim.x + threadIdx.x;
  int wid = gid >> 6, lane = gid & 63;
  if (wid >= NSEQ) return;
  int b = wid / SS;
  const float* ar = a + (size_t)wid * 512;
  const float* rr = r + (size_t)b * 512;
  float sum = 0.f;
  for (int i = lane; i < 512; i += 64) sum += ar[i] * rr[i];
  for (int off = 32; off > 0; off >>= 1) sum += __shfl_down(sum, off);
  if (lane == 0) e[wid] = sum;
}

__global__ void softmax_k(const float* __restrict__ e, const float* __restrict__ mask,
                          float* __restrict__ alpha) {
  __shared__ float red[256];
  int b = blockIdx.x, tid = threadIdx.x;
  float v = (tid < SS) ? e[b * SS + tid] : -1e30f;
  red[tid] = v; __syncthreads();
  for (int s = 128; s > 0; s >>= 1) { if (tid < s) red[tid] = fmaxf(red[tid], red[tid + s]); __syncthreads(); }
  float mx = red[0]; __syncthreads();
  float ex = (tid < SS) ? expf(v - mx) : 0.f;
  red[tid] = ex; __syncthreads();
  for (int s = 128; s > 0; s >>= 1) { if (tid < s) red[tid] += red[tid + s]; __syncthreads(); }
  float denom = red[0];
  if (tid < SS) alpha[b * SS + tid] = ex / denom * mask[b * SS + tid];
}

__global__ void cattn_k(const float* __restrict__ alpha, const float* __restrict__ sc,
                        float* __restrict__ c) {
  int b = blockIdx.x, d = threadIdx.x;  // 512 threads
  float sum = 0.f;
  for (int s = 0; s < SS; ++s)
    sum += alpha[b * SS + s] * sc[(size_t)(b * SS + s) * 512 + d];
  c[b * 512 + d] = sum;
}

// o[b] = sum_d c[d] * (sum_e M[d][e] * r[b][e]) + b0
__global__ void final_k(const float* __restrict__ cattn, const float* __restrict__ Mw,
                        const float* __restrict__ r, const float* __restrict__ bsc,
                        float* __restrict__ out) {
  __shared__ float red[256];
  int b = blockIdx.x, tid = threadIdx.x;
  const float* rb = r + (size_t)b * 512;
  float part = 0.f;
  for (int d = tid; d < 512; d += 256) {
    const float* mrow = Mw + (size_t)d * 512;
    float t = 0.f;
    for (int e = 0; e < 512; ++e) t += mrow[e] * rb[e];
    part += cattn[b * 512 + d] * t;
  }
  red[tid] = part; __syncthreads();
  for (int s = 128; s > 0; s >>= 1) { if (tid < s) red[tid] += red[tid + s]; __syncthreads(); }
  if (tid == 0) out[b] = red[0] + bsc[0];
}

extern "C" void kernel_launch(void* const* d_in, const int* in_sizes, int n_in,
                              void* d_out, int out_size, void* d_ws, size_t ws_size,
                              hipStream_t stream) {
  const int*   x1     = (const int*)d_in[0];
  const int*   x2     = (const int*)d_in[1];
  const int*   keys_c = (const int*)d_in[2];
  const int*   keys_r = (const int*)d_in[3];
  const float* x1mask = (const float*)d_in[4];
  const float* emb    = (const float*)d_in[5];
  const float* kWif   = (const float*)d_in[6];
  const float* kWhf   = (const float*)d_in[7];
  const float* kbif   = (const float*)d_in[8];
  const float* kbhf   = (const float*)d_in[9];
  const float* kWib   = (const float*)d_in[10];
  const float* kWhb   = (const float*)d_in[11];
  const float* kbib   = (const float*)d_in[12];
  const float* kbhb   = (const float*)d_in[13];
  const float* eWif   = (const float*)d_in[14];
  const float* eWhf   = (const float*)d_in[15];
  const float* ebif   = (const float*)d_in[16];
  const float* ebhf   = (const float*)d_in[17];
  const float* eWib   = (const float*)d_in[18];
  const float* eWhb   = (const float*)d_in[19];
  const float* ebib   = (const float*)d_in[20];
  const float* ebhb   = (const float*)d_in[21];
  const float* attnW  = (const float*)d_in[22];
  const float* attnb  = (const float*)d_in[23];
  const float* Mw     = (const float*)d_in[24];
  const float* bsc    = (const float*)d_in[25];
  float* out = (float*)d_out;

  char* base = (char*)d_ws;
  size_t off = 0;
  auto take = [&](size_t bytes) -> void* {
    void* p = base + off; off += (bytes + 255) & ~(size_t)255; return p;
  };

  // ---- shared (live whole launch) ~16.6 MB ----
  u16* kWif_bf = (u16*)take((size_t)G3 * EP * 2);
  u16* kWib_bf = (u16*)take((size_t)G3 * EP * 2);
  u16* kWhf_bf = (u16*)take((size_t)G3 * HH * 2);
  u16* kWhb_bf = (u16*)take((size_t)G3 * HH * 2);
  u16* eWif_bf = (u16*)take((size_t)G3 * EHP * 2);
  u16* eWib_bf = (u16*)take((size_t)G3 * EHP * 2);
  u16* eWhf_bf = (u16*)take((size_t)G3 * HH * 2);
  u16* eWhb_bf = (u16*)take((size_t)G3 * HH * 2);
  u16* attnW_bf = (u16*)take((size_t)512 * 512 * 2);
  u16* xe_bf   = (u16*)take((size_t)NROW * EHP * 2);

  size_t pbase = off;
  // ---- phase 1 (key GRU) ~213 MB ----
  u16*   emb_bf = (u16*)take((size_t)VV * EP * 2);
  u16*   TF     = (u16*)take((size_t)VV * G3 * 2);
  u16*   TB     = (u16*)take((size_t)VV * G3 * 2);
  float* h_key  = (float*)take((size_t)NKEY * HH * 4);
  u16*   h_key_bf = (u16*)take((size_t)NKEY * HH * 2);
  float* gh_key = (float*)take((size_t)NKEY * G3 * 4);

  // ---- phase 2 (main GRU + attention) overlaps phase 1 (~90 MB < 213 MB) ----
  off = pbase;
  float* Gf = (float*)take((size_t)NROW * G3 * 4);
  float* Gb = (float*)take((size_t)NROW * G3 * 4);
  float* h_main = (float*)take((size_t)128 * HH * 4);
  u16*   h_main_bf = (u16*)take((size_t)128 * HH * 2);
  float* gh_main = (float*)take((size_t)128 * G3 * 4);
  float* sc = (float*)take((size_t)NSEQ * 512 * 4);
  u16*   sc_bf = (u16*)take((size_t)NSEQ * 512 * 2);
  float* rvec = (float*)take((size_t)BB * 512 * 4);
  float* abuf = (float*)take((size_t)NSEQ * 512 * 4);
  float* energ = (float*)take((size_t)BB * SS * 4);
  float* alpha = (float*)take((size_t)BB * SS * 4);
  float* c_attn = (float*)take((size_t)BB * 512 * 4);

  auto cvt = [&](const float* s, u16* d, int rows, int K, int ldp) {
    int tot = rows * ldp;
    cvt_pad<<<(tot + 255) / 256, 256, 0, stream>>>(s, d, rows, K, ldp);
  };
  auto gemm = [&](const u16* A, const u16* B0, const u16* B1, int halfM,
                  float* C, u16* Cbf, const float* b0, const float* b1,
                  int M, int N, int K, int lda, int ldb, int ldc) {
    long long waves = (long long)(M / 16) * (N / 16);
    int blocks = (int)((waves * 64 + 255) / 256);
    gemm_bt<<<blocks, 256, 0, stream>>>(A, B0, B1, halfM, C, Cbf, b0, b1,
                                        M, N, K, lda, ldb, ldc);
  };

  // Convert weights + emb to bf16 (padded)
  cvt(emb, emb_bf, VV, EE, EP);
  cvt(kWif, kWif_bf, G3, EE, EP);
  cvt(kWib, kWib_bf, G3, EE, EP);
  cvt(kWhf, kWhf_bf, G3, HH, HH);
  cvt(kWhb, kWhb_bf, G3, HH, HH);
  cvt(eWif, eWif_bf, G3, 556, EHP);
  cvt(eWib, eWib_bf, G3, 556, EHP);
  cvt(eWhf, eWhf_bf, G3, HH, HH);
  cvt(eWhb, eWhb_bf, G3, HH, HH);
  cvt(attnW, attnW_bf, 512, 512, 512);

  // Key-GRU input tables: T[v] = emb[v] @ Wih.T + bih  (bf16 out)
  gemm(emb_bf, kWif_bf, kWif_bf, VV, nullptr, TF, kbif, kbif, VV, G3, EP, EP, EP, G3);
  gemm(emb_bf, kWib_bf, kWib_bf, VV, nullptr, TB, kbib, kbib, VV, G3, EP, EP, EP, G3);

  // Key GRU recurrence: 44 steps over batch 20480 (both sets, both dirs)
  hipMemsetAsync(h_key, 0, (size_t)NKEY * HH * 4, stream);
  hipMemsetAsync(h_key_bf, 0, (size_t)NKEY * HH * 2, stream);
  for (int t = 0; t < KK; ++t) {
    gemm(h_key_bf, kWhf_bf, kWhb_bf, NROW, gh_key, nullptr, kbhf, kbhb,
         NKEY, G3, HH, HH, HH, G3);
    key_update<<<(NKEY * HH + 255) / 256, 256, 0, stream>>>(
        gh_key, TF, TB, keys_c, keys_r, h_key, h_key_bf, t);
  }

  // Build main-GRU inputs [emb[x], hf+hb] (bf16, padded to 576)
  build_xe<<<(NROW * EHP + 255) / 256, 256, 0, stream>>>(emb, x1, x2, h_key, xe_bf);

  // Main-GRU input transforms for all timesteps
  gemm(xe_bf, eWif_bf, eWif_bf, NROW, Gf, nullptr, ebif, ebif, NROW, G3, EHP, EHP, EHP, G3);
  gemm(xe_bf, eWib_bf, eWib_bf, NROW, Gb, nullptr, ebib, ebib, NROW, G3, EHP, EHP, EHP, G3);

  // Main GRU recurrence: 160 steps over batch 128 (x1/x2 × fwd/bwd)
  hipMemsetAsync(h_main, 0, (size_t)128 * HH * 4, stream);
  hipMemsetAsync(h_main_bf, 0, (size_t)128 * HH * 2, stream);
  for (int t = 0; t < SS; ++t) {
    gemm(h_main_bf, eWhf_bf, eWhb_bf, 64, gh_main, nullptr, ebhf, ebhb,
         128, G3, HH, HH, HH, G3);
    main_update<<<(128 * HH + 255) / 256, 256, 0, stream>>>(
        gh_main, Gf, Gb, h_main, h_main_bf, sc, sc_bf, t);
  }
  extract_r<<<(BB * 512 + 255) / 256, 256, 0, stream>>>(h_main, rvec);

  // Attention
  gemm(sc_bf, attnW_bf, attnW_bf, NSEQ, abuf, nullptr, attnb, attnb,
       NSEQ, 512, 512, 512, 512, 512);
  energies_k<<<(NSEQ * 64 + 255) / 256, 256, 0, stream>>>(abuf, rvec, energ);
  softmax_k<<<BB, 256, 0, stream>>>(energ, x1mask, alpha);
  cattn_k<<<BB, 512, 0, stream>>>(alpha, sc, c_attn);
  final_k<<<BB, 256, 0, stream>>>(c_attn, Mw, rvec, bsc, out);
}

// Round 2
// 5888.919 us; speedup vs baseline: 1.3794x; 1.3794x over previous
//
#include <hip/hip_runtime.h>
#include <hip/hip_bf16.h>

// Dims (fixed by the problem)
#define BB 32
#define SS 160
#define KK 44
#define EE 300
#define HH 256
#define VV 32000
#define G3 768      // 3*H
#define EHP 576     // 556 padded to mult of 32
#define EP  320     // 300 padded to mult of 32
#define NSEQ 5120   // B*S
#define NROW 10240  // 2 key sets * NSEQ
#define NKEY 20480  // 2 dirs * NROW

typedef unsigned short u16;
typedef __attribute__((ext_vector_type(8))) short bf16x8;
typedef __attribute__((ext_vector_type(4))) float f32x4;
typedef __attribute__((ext_vector_type(4))) unsigned short u16x4;

static __device__ __forceinline__ u16 f2bf(float f) {
  union { float f; unsigned u; } x; x.f = f;
  unsigned u = x.u;
  unsigned r = (u + 0x7fffu + ((u >> 16) & 1u)) >> 16;
  return (u16)r;
}
static __device__ __forceinline__ float bf2f(u16 v) {
  union { unsigned u; float f; } x; x.u = ((unsigned)v) << 16;
  return x.f;
}
static __device__ __forceinline__ float fsig(float x) {
  float e = __expf(-x);
  return __builtin_amdgcn_rcpf(1.f + e);
}
static __device__ __forceinline__ float ftanh(float x) {
  float e = __expf(2.f * x);
  return 1.f - 2.f * __builtin_amdgcn_rcpf(1.f + e);
}

// fp32 (rows,K) -> bf16 (rows,ldp) with zero pad cols K..ldp
__global__ void cvt_pad(const float* __restrict__ src, u16* __restrict__ dst,
                        int rows, int K, int ldp) {
  int idx = blockIdx.x * blockDim.x + threadIdx.x;
  int tot = rows * ldp;
  if (idx >= tot) return;
  int c = idx % ldp; int r = idx / ldp;
  float v = (c < K) ? src[(size_t)r * K + c] : 0.f;
  dst[idx] = f2bf(v);
}

// C = A @ B^T + bias; 2 row-tiles per wave (B-frag reuse).
// A:(M,lda) bf16, B:(N,ldb) bf16, M%32==0, N%16==0, K%32==0.
__global__ void gemm_bt2(const u16* __restrict__ A, const u16* __restrict__ B,
                         float* __restrict__ C, u16* __restrict__ Cbf,
                         const float* __restrict__ bias,
                         int M, int N, int K, int lda, int ldb, int ldc) {
  int gid = blockIdx.x * blockDim.x + threadIdx.x;
  int wid = gid >> 6, lane = gid & 63;
  int ntiles = N >> 4;
  int total = (M >> 5) * ntiles;
  if (wid >= total) return;
  int tm = wid / ntiles, tn = wid - tm * ntiles;
  int rbase = tm << 5;
  int m = lane & 15, quad = lane >> 4;
  const u16* ap0 = A + (size_t)(rbase + m) * lda + quad * 8;
  const u16* ap1 = ap0 + (size_t)16 * lda;
  const u16* bp = B + (size_t)((tn << 4) + m) * ldb + quad * 8;
  f32x4 acc0 = {0.f, 0.f, 0.f, 0.f}, acc1 = {0.f, 0.f, 0.f, 0.f};
  for (int k = 0; k < K; k += 32) {
    bf16x8 bv = *(const bf16x8*)(bp + k);
    bf16x8 a0 = *(const bf16x8*)(ap0 + k);
    bf16x8 a1 = *(const bf16x8*)(ap1 + k);
    acc0 = __builtin_amdgcn_mfma_f32_16x16x32_bf16(a0, bv, acc0, 0, 0, 0);
    acc1 = __builtin_amdgcn_mfma_f32_16x16x32_bf16(a1, bv, acc1, 0, 0, 0);
  }
  int col = (tn << 4) + m;
  float bv = bias ? bias[col] : 0.f;
  int orow0 = rbase + quad * 4;
  if (Cbf) {
    #pragma unroll
    for (int i = 0; i < 4; ++i) {
      Cbf[(size_t)(orow0 + i) * ldc + col] = f2bf(acc0[i] + bv);
      Cbf[(size_t)(orow0 + 16 + i) * ldc + col] = f2bf(acc1[i] + bv);
    }
  } else {
    #pragma unroll
    for (int i = 0; i < 4; ++i) {
      C[(size_t)(orow0 + i) * ldc + col] = acc0[i] + bv;
      C[(size_t)(orow0 + 16 + i) * ldc + col] = acc1[i] + bv;
    }
  }
}

// ---- Persistent key-GRU kernel ----
// 640 blocks x 256 threads; block owns 32 consecutive rows of the 20480-row
// batch (fwd rows [0,10240): keys_c then keys_r; bwd rows [10240,20480)).
// h fp32 in registers (32/thread), h bf16 in LDS (GEMM A), gh in 48KB LDS
// processed as two 16-row passes. 44 steps inside one launch.
template <int P>
static __device__ __forceinline__ void key_upd(
    int step, int urow_l, int uc, int seq0, int bwd,
    const int* __restrict__ keys, const u16* __restrict__ T,
    const float* biasL, const float* ghL, u16* hbf, float* hreg) {
  int grow_l = P * 16 + urow_l;
  int seq = seq0 + grow_l;
  int tt = bwd ? (KK - 1 - step) : step;
  int tok = keys[seq * KK + tt];
  const u16* gi = T + (size_t)tok * G3;
  #pragma unroll
  for (int i = 0; i < 4; ++i) {
    int j = uc + 64 * i;
    f32x4 ghr = *(const f32x4*)&ghL[urow_l * 768 + j];
    f32x4 ghz = *(const f32x4*)&ghL[urow_l * 768 + 256 + j];
    f32x4 ghn = *(const f32x4*)&ghL[urow_l * 768 + 512 + j];
    u16x4 gir = *(const u16x4*)(gi + j);
    u16x4 giz = *(const u16x4*)(gi + 256 + j);
    u16x4 gin = *(const u16x4*)(gi + 512 + j);
    f32x4 br = *(const f32x4*)&biasL[j];
    f32x4 bz = *(const f32x4*)&biasL[256 + j];
    f32x4 bn = *(const f32x4*)&biasL[512 + j];
    u16x4 hbv;
    #pragma unroll
    for (int c = 0; c < 4; ++c) {
      float r = fsig(bf2f(gir[c]) + ghr[c] + br[c]);
      float z = fsig(bf2f(giz[c]) + ghz[c] + bz[c]);
      float n = ftanh(bf2f(gin[c]) + r * (ghn[c] + bn[c]));
      float hnew = (1.f - z) * n + z * hreg[P * 16 + i * 4 + c];
      hreg[P * 16 + i * 4 + c] = hnew;
      hbv[c] = f2bf(hnew);
    }
    *(u16x4*)&hbf[grow_l * 256 + j] = hbv;
  }
}

__global__ __launch_bounds__(256, 2) void key_gru_persist(
    const u16* __restrict__ Whf, const u16* __restrict__ Whb,
    const float* __restrict__ bhf, const float* __restrict__ bhb,
    const u16* __restrict__ TF, const u16* __restrict__ TB,
    const int* __restrict__ keys_c, const int* __restrict__ keys_r,
    float* __restrict__ h_out) {
  __shared__ u16 hbf[32 * 256];     // 16 KB
  __shared__ float ghL[16 * 768];   // 48 KB
  __shared__ float biasL[768];      // 3 KB
  int blk = blockIdx.x;
  int row0 = blk * 32;
  int bwd = row0 >= NROW;
  int sn0 = row0 - (bwd ? NROW : 0);
  int isR = sn0 >= NSEQ;
  int seq0 = sn0 - (isR ? NSEQ : 0);
  const u16* W = bwd ? Whb : Whf;
  const float* bias = bwd ? bhb : bhf;
  const u16* T = bwd ? TB : TF;
  const int* keys = isR ? keys_r : keys_c;

  int t = threadIdx.x;
  int w = t >> 6, lane = t & 63, m = lane & 15, quad = lane >> 4;
  int urow_l = t >> 4;          // 0..15
  int uc = (t & 15) * 4;        // col base; elements at uc + 64*i

  for (int i = t; i < 32 * 256; i += 256) hbf[i] = 0;
  for (int i = t; i < 768; i += 256) biasL[i] = bias[i];
  float hreg[32];
  #pragma unroll
  for (int i = 0; i < 32; ++i) hreg[i] = 0.f;
  __syncthreads();

  for (int step = 0; step < KK; ++step) {
    // A fragments (both 16-row tiles) from LDS
    bf16x8 a0[8], a1[8];
    #pragma unroll
    for (int k = 0; k < 8; ++k) {
      a0[k] = *(const bf16x8*)&hbf[m * 256 + quad * 8 + k * 32];
      a1[k] = *(const bf16x8*)&hbf[(16 + m) * 256 + quad * 8 + k * 32];
    }
    f32x4 acc1s[12];
    #pragma unroll
    for (int ci = 0; ci < 12; ++ci) {
      int cb = (w * 12 + ci) << 4;
      const u16* bp = W + (size_t)(cb + m) * 256 + quad * 8;
      f32x4 acc0 = {0.f, 0.f, 0.f, 0.f};
      f32x4 acc1 = {0.f, 0.f, 0.f, 0.f};
      #pragma unroll
      for (int k = 0; k < 8; ++k) {
        bf16x8 bv = *(const bf16x8*)(bp + k * 32);
        acc0 = __builtin_amdgcn_mfma_f32_16x16x32_bf16(a0[k], bv, acc0, 0, 0, 0);
        acc1 = __builtin_amdgcn_mfma_f32_16x16x32_bf16(a1[k], bv, acc1, 0, 0, 0);
      }
      acc1s[ci] = acc1;
      #pragma unroll
      for (int i = 0; i < 4; ++i)
        ghL[(quad * 4 + i) * 768 + cb + m] = acc0[i];
    }
    __syncthreads();
    key_upd<0>(step, urow_l, uc, seq0, bwd, keys, T, biasL, ghL, hbf, hreg);
    __syncthreads();
    #pragma unroll
    for (int ci = 0; ci < 12; ++ci) {
      int cb = (w * 12 + ci) << 4;
      #pragma unroll
      for (int i = 0; i < 4; ++i)
        ghL[(quad * 4 + i) * 768 + cb + m] = acc1s[ci][i];
    }
    __syncthreads();
    key_upd<1>(step, urow_l, uc, seq0, bwd, keys, T, biasL, ghL, hbf, hreg);
    __syncthreads();
  }
  // write fp32 finals
  #pragma unroll
  for (int p = 0; p < 2; ++p) {
    int grow = row0 + p * 16 + urow_l;
    #pragma unroll
    for (int i = 0; i < 4; ++i) {
      f32x4 v;
      #pragma unroll
      for (int c = 0; c < 4; ++c) v[c] = hreg[p * 16 + i * 4 + c];
      *(f32x4*)&h_out[(size_t)grow * 256 + uc + 64 * i] = v;
    }
  }
}

// Build concat inputs for the main GRU, bf16 padded.
__global__ void build_xe(const float* __restrict__ emb, const int* __restrict__ x1,
                         const int* __restrict__ x2, const float* __restrict__ hk,
                         u16* __restrict__ xe) {
  int idx = blockIdx.x * blockDim.x + threadIdx.x;
  if (idx >= NROW * EHP) return;
  int c = idx % EHP; int rr = idx / EHP;
  int isX2 = rr >= NSEQ;
  int seq = rr - (isX2 ? NSEQ : 0);
  float v;
  if (c < EE) {
    int tok = (isX2 ? x2 : x1)[seq];
    v = emb[(size_t)tok * EE + c];
  } else if (c < EE + HH) {
    int j = c - EE;
    int frow = (isX2 ? NSEQ : 0) + seq;
    v = hk[(size_t)frow * HH + j] + hk[(size_t)(NROW + frow) * HH + j];
  } else {
    v = 0.f;
  }
  xe[idx] = f2bf(v);
}

// ---- Fused main-GRU step: GEMM (128x768x256) + gate update, one launch ----
// 8 blocks; block rt owns rows [rt*16, rt*16+16). Row layout: row = q*32+bb,
// q: 0=x1 fwd, 1=x2 fwd, 2=x1 bwd, 3=x2 bwd.
__global__ __launch_bounds__(256) void main_gru_step(
    const u16* __restrict__ Wf, const u16* __restrict__ Wb,
    const float* __restrict__ bfw, const float* __restrict__ bbw,
    const float* __restrict__ Gf, const float* __restrict__ Gb,
    float* __restrict__ h, u16* __restrict__ hb,
    float* __restrict__ sc, u16* __restrict__ scbf, int step) {
  __shared__ float ghL[16 * 768];
  int rt = blockIdx.x;
  int rbase = rt << 4;
  int fwd = rt < 4;
  const u16* W = fwd ? Wf : Wb;
  const float* bias = fwd ? bfw : bbw;
  int t = threadIdx.x, w = t >> 6, lane = t & 63, m = lane & 15, quad = lane >> 4;
  bf16x8 a[8];
  #pragma unroll
  for (int k = 0; k < 8; ++k)
    a[k] = *(const bf16x8*)&hb[(size_t)(rbase + m) * 256 + quad * 8 + k * 32];
  #pragma unroll
  for (int ci = 0; ci < 12; ++ci) {
    int cb = (w * 12 + ci) << 4;
    const u16* bp = W + (size_t)(cb + m) * 256 + quad * 8;
    f32x4 acc = {0.f, 0.f, 0.f, 0.f};
    #pragma unroll
    for (int k = 0; k < 8; ++k) {
      bf16x8 bv = *(const bf16x8*)(bp + k * 32);
      acc = __builtin_amdgcn_mfma_f32_16x16x32_bf16(a[k], bv, acc, 0, 0, 0);
    }
    #pragma unroll
    for (int i = 0; i < 4; ++i)
      ghL[(quad * 4 + i) * 768 + cb + m] = acc[i];
  }
  __syncthreads();
  int urow = t >> 4, uc = (t & 15) * 4;
  int grow = rbase + urow;
  int q = grow >> 5, bb2 = grow & 31;
  int bwd = q >> 1, isX2 = q & 1;
  int s = bwd ? (SS - 1 - step) : step;
  const float* gi = (bwd ? Gb : Gf) + (size_t)(isX2 * NSEQ + bb2 * SS + s) * G3;
  #pragma unroll
  for (int i = 0; i < 4; ++i) {
    int j = uc + 64 * i;
    f32x4 ghr = *(const f32x4*)&ghL[urow * 768 + j];
    f32x4 ghz = *(const f32x4*)&ghL[urow * 768 + 256 + j];
    f32x4 ghn = *(const f32x4*)&ghL[urow * 768 + 512 + j];
    f32x4 gir = *(const f32x4*)&gi[j];
    f32x4 giz = *(const f32x4*)&gi[256 + j];
    f32x4 gin = *(const f32x4*)&gi[512 + j];
    f32x4 br = *(const f32x4*)&bias[j];
    f32x4 bz = *(const f32x4*)&bias[256 + j];
    f32x4 bn = *(const f32x4*)&bias[512 + j];
    f32x4 hold = *(const f32x4*)&h[(size_t)grow * 256 + j];
    f32x4 hnew; u16x4 hbv;
    #pragma unroll
    for (int c = 0; c < 4; ++c) {
      float r = fsig(gir[c] + ghr[c] + br[c]);
      float z = fsig(giz[c] + ghz[c] + bz[c]);
      float n = ftanh(gin[c] + r * (ghn[c] + bn[c]));
      hnew[c] = (1.f - z) * n + z * hold[c];
      hbv[c] = f2bf(hnew[c]);
    }
    *(f32x4*)&h[(size_t)grow * 256 + j] = hnew;
    *(u16x4*)&hb[(size_t)grow * 256 + j] = hbv;
    if (!isX2) {
      size_t o = (size_t)(bb2 * SS + s) * 512 + (bwd ? 256 : 0) + j;
      *(f32x4*)&sc[o] = hnew;
      *(u16x4*)&scbf[o] = hbv;
    }
  }
}

// r = concat(r1f, r1b) (+ bf16 copy)
__global__ void extract_r(const float* __restrict__ h, float* __restrict__ r,
                          u16* __restrict__ rbf) {
  int idx = blockIdx.x * blockDim.x + threadIdx.x;
  if (idx >= BB * 512) return;
  int bb = idx >> 9, j = idx & 511;
  int row = (j < 256) ? (32 + bb) : (96 + bb);
  float v = h[row * HH + (j & 255)];
  r[idx] = v;
  rbf[idx] = f2bf(v);
}

__global__ void energies_k(const float* __restrict__ a, const float* __restrict__ r,
                           float* __restrict__ e) {
  int gid = blockIdx.x * blockDim.x + threadIdx.x;
  int wid = gid >> 6, lane = gid & 63;
  if (wid >= NSEQ) return;
  int b = wid / SS;
  const float* ar = a + (size_t)wid * 512;
  const float* rr = r + (size_t)b * 512;
  float sum = 0.f;
  for (int i = lane; i < 512; i += 64) sum += ar[i] * rr[i];
  for (int off = 32; off > 0; off >>= 1) sum += __shfl_down(sum, off);
  if (lane == 0) e[wid] = sum;
}

__global__ void softmax_k(const float* __restrict__ e, const float* __restrict__ mask,
                          float* __restrict__ alpha) {
  __shared__ float red[256];
  int b = blockIdx.x, tid = threadIdx.x;
  float v = (tid < SS) ? e[b * SS + tid] : -1e30f;
  red[tid] = v; __syncthreads();
  for (int s = 128; s > 0; s >>= 1) { if (tid < s) red[tid] = fmaxf(red[tid], red[tid + s]); __syncthreads(); }
  float mx = red[0]; __syncthreads();
  float ex = (tid < SS) ? expf(v - mx) : 0.f;
  red[tid] = ex; __syncthreads();
  for (int s = 128; s > 0; s >>= 1) { if (tid < s) red[tid] += red[tid + s]; __syncthreads(); }
  float denom = red[0];
  if (tid < SS) alpha[b * SS + tid] = ex / denom * mask[b * SS + tid];
}

__global__ void cattn_k(const float* __restrict__ alpha, const float* __restrict__ sc,
                        float* __restrict__ c) {
  int b = blockIdx.x, d = threadIdx.x;  // 512 threads
  float sum = 0.f;
  for (int s = 0; s < SS; ++s)
    sum += alpha[b * SS + s] * sc[(size_t)(b * SS + s) * 512 + d];
  c[b * 512 + d] = sum;
}

// o[b] = sum_d c[b,d]*v[b,d] + b0   (v = r @ M^T from gemm)
__global__ void final_dot(const float* __restrict__ c, const float* __restrict__ v,
                          const float* __restrict__ bsc, float* __restrict__ out) {
  int b = blockIdx.x, lane = threadIdx.x;
  float s = 0.f;
  for (int i = lane; i < 512; i += 64) s += c[b * 512 + i] * v[b * 512 + i];
  for (int off = 32; off > 0; off >>= 1) s += __shfl_down(s, off);
  if (lane == 0) out[b] = s + bsc[0];
}

extern "C" void kernel_launch(void* const* d_in, const int* in_sizes, int n_in,
                              void* d_out, int out_size, void* d_ws, size_t ws_size,
                              hipStream_t stream) {
  const int*   x1     = (const int*)d_in[0];
  const int*   x2     = (const int*)d_in[1];
  const int*   keys_c = (const int*)d_in[2];
  const int*   keys_r = (const int*)d_in[3];
  const float* x1mask = (const float*)d_in[4];
  const float* emb    = (const float*)d_in[5];
  const float* kWif   = (const float*)d_in[6];
  const float* kWhf   = (const float*)d_in[7];
  const float* kbif   = (const float*)d_in[8];
  const float* kbhf   = (const float*)d_in[9];
  const float* kWib   = (const float*)d_in[10];
  const float* kWhb   = (const float*)d_in[11];
  const float* kbib   = (const float*)d_in[12];
  const float* kbhb   = (const float*)d_in[13];
  const float* eWif   = (const float*)d_in[14];
  const float* eWhf   = (const float*)d_in[15];
  const float* ebif   = (const float*)d_in[16];
  const float* ebhf   = (const float*)d_in[17];
  const float* eWib   = (const float*)d_in[18];
  const float* eWhb   = (const float*)d_in[19];
  const float* ebib   = (const float*)d_in[20];
  const float* ebhb   = (const float*)d_in[21];
  const float* attnW  = (const float*)d_in[22];
  const float* attnb  = (const float*)d_in[23];
  const float* Mw     = (const float*)d_in[24];
  const float* bsc    = (const float*)d_in[25];
  float* out = (float*)d_out;

  char* base = (char*)d_ws;
  size_t off = 0;
  auto take = [&](size_t bytes) -> void* {
    void* p = base + off; off += (bytes + 255) & ~(size_t)255; return p;
  };

  // ---- shared (live whole launch) ~17 MB ----
  u16* kWif_bf = (u16*)take((size_t)G3 * EP * 2);
  u16* kWib_bf = (u16*)take((size_t)G3 * EP * 2);
  u16* kWhf_bf = (u16*)take((size_t)G3 * HH * 2);
  u16* kWhb_bf = (u16*)take((size_t)G3 * HH * 2);
  u16* eWif_bf = (u16*)take((size_t)G3 * EHP * 2);
  u16* eWib_bf = (u16*)take((size_t)G3 * EHP * 2);
  u16* eWhf_bf = (u16*)take((size_t)G3 * HH * 2);
  u16* eWhb_bf = (u16*)take((size_t)G3 * HH * 2);
  u16* attnW_bf = (u16*)take((size_t)512 * 512 * 2);
  u16* M_bf    = (u16*)take((size_t)512 * 512 * 2);
  u16* xe_bf   = (u16*)take((size_t)NROW * EHP * 2);

  size_t pbase = off;
  // ---- phase 1 (key GRU) ----
  u16*   emb_bf = (u16*)take((size_t)VV * EP * 2);     // 20.5 MB
  u16*   TF     = (u16*)take((size_t)VV * G3 * 2);     // 49.2 MB
  u16*   TB     = (u16*)take((size_t)VV * G3 * 2);     // 49.2 MB
  float* h_key  = (float*)take((size_t)NKEY * HH * 4); // 21 MB (at pbase+118.9MB)

  // ---- phase 2 overlaps emb_bf/TF/TB (dead after key phase); ~91 MB < 118.9 ----
  off = pbase;
  float* Gf = (float*)take((size_t)NROW * G3 * 4);
  float* Gb = (float*)take((size_t)NROW * G3 * 4);
  float* h_main = (float*)take((size_t)128 * HH * 4);
  u16*   h_main_bf = (u16*)take((size_t)128 * HH * 2);
  float* sc = (float*)take((size_t)NSEQ * 512 * 4);
  u16*   sc_bf = (u16*)take((size_t)NSEQ * 512 * 2);
  float* rvec = (float*)take((size_t)BB * 512 * 4);
  u16*   r_bf = (u16*)take((size_t)BB * 512 * 2);
  float* abuf = (float*)take((size_t)NSEQ * 512 * 4);
  float* energ = (float*)take((size_t)BB * SS * 4);
  float* alpha = (float*)take((size_t)BB * SS * 4);
  float* c_attn = (float*)take((size_t)BB * 512 * 4);
  float* vbuf = (float*)take((size_t)BB * 512 * 4);

  auto cvt = [&](const float* s, u16* d, int rows, int K, int ldp) {
    int tot = rows * ldp;
    cvt_pad<<<(tot + 255) / 256, 256, 0, stream>>>(s, d, rows, K, ldp);
  };
  auto gemm2 = [&](const u16* A, const u16* B, float* C, u16* Cbf, const float* bias,
                   int M, int N, int K, int lda, int ldb, int ldc) {
    long long waves = (long long)(M >> 5) * (N >> 4);
    int blocks = (int)((waves * 64 + 255) / 256);
    gemm_bt2<<<blocks, 256, 0, stream>>>(A, B, C, Cbf, bias, M, N, K, lda, ldb, ldc);
  };

  // Convert weights + emb to bf16 (padded)
  cvt(emb, emb_bf, VV, EE, EP);
  cvt(kWif, kWif_bf, G3, EE, EP);
  cvt(kWib, kWib_bf, G3, EE, EP);
  cvt(kWhf, kWhf_bf, G3, HH, HH);
  cvt(kWhb, kWhb_bf, G3, HH, HH);
  cvt(eWif, eWif_bf, G3, 556, EHP);
  cvt(eWib, eWib_bf, G3, 556, EHP);
  cvt(eWhf, eWhf_bf, G3, HH, HH);
  cvt(eWhb, eWhb_bf, G3, HH, HH);
  cvt(attnW, attnW_bf, 512, 512, 512);
  cvt(Mw, M_bf, 512, 512, 512);

  // Key-GRU input tables: T[v] = emb[v] @ Wih.T + bih (bf16 out)
  gemm2(emb_bf, kWif_bf, nullptr, TF, kbif, VV, G3, EP, EP, EP, G3);
  gemm2(emb_bf, kWib_bf, nullptr, TB, kbib, VV, G3, EP, EP, EP, G3);

  // Key GRU: one persistent launch, 44 internal steps
  key_gru_persist<<<640, 256, 0, stream>>>(kWhf_bf, kWhb_bf, kbhf, kbhb,
                                           TF, TB, keys_c, keys_r, h_key);

  // Build main-GRU inputs [emb[x], hf+hb]
  build_xe<<<(NROW * EHP + 255) / 256, 256, 0, stream>>>(emb, x1, x2, h_key, xe_bf);

  // Main-GRU input transforms for all timesteps (overwrites dead emb_bf/TF)
  gemm2(xe_bf, eWif_bf, Gf, nullptr, ebif, NROW, G3, EHP, EHP, EHP, G3);
  gemm2(xe_bf, eWib_bf, Gb, nullptr, ebib, NROW, G3, EHP, EHP, EHP, G3);

  // Main GRU: 160 fused steps
  hipMemsetAsync(h_main, 0, (size_t)128 * HH * 4, stream);
  hipMemsetAsync(h_main_bf, 0, (size_t)128 * HH * 2, stream);
  for (int t = 0; t < SS; ++t) {
    main_gru_step<<<8, 256, 0, stream>>>(eWhf_bf, eWhb_bf, ebhf, ebhb,
                                         Gf, Gb, h_main, h_main_bf, sc, sc_bf, t);
  }
  extract_r<<<(BB * 512 + 255) / 256, 256, 0, stream>>>(h_main, rvec, r_bf);

  // Attention + readout
  gemm2(sc_bf, attnW_bf, abuf, nullptr, attnb, NSEQ, 512, 512, 512, 512, 512);
  energies_k<<<(NSEQ * 64 + 255) / 256, 256, 0, stream>>>(abuf, rvec, energ);
  softmax_k<<<BB, 256, 0, stream>>>(energ, x1mask, alpha);
  cattn_k<<<BB, 512, 0, stream>>>(alpha, sc, c_attn);
  gemm2(r_bf, M_bf, vbuf, nullptr, nullptr, BB, 512, 512, 512, 512, 512);
  final_dot<<<BB, 64, 0, stream>>>(c_attn, vbuf, bsc, out);
}

// Round 3
// 4969.559 us; speedup vs baseline: 1.6346x; 1.1850x over previous
//
#include <hip/hip_runtime.h>
#include <hip/hip_bf16.h>

#define BB 32
#define SS 160
#define KK 44
#define EE 300
#define HH 256
#define VV 32000
#define G3 768
#define EHP 576
#define EP  320
#define NSEQ 5120
#define NROW 10240
#define NKEY 20480

typedef unsigned short u16;
typedef __attribute__((ext_vector_type(8))) short bf16x8;
typedef __attribute__((ext_vector_type(4))) float f32x4;
typedef __attribute__((ext_vector_type(4))) int i32x4;

static __device__ __forceinline__ u16 f2bf(float f) {
  union { float f; unsigned u; } x; x.f = f;
  unsigned u = x.u;
  unsigned r = (u + 0x7fffu + ((u >> 16) & 1u)) >> 16;
  return (u16)r;
}
static __device__ __forceinline__ float bf2f(u16 v) {
  union { unsigned u; float f; } x; x.u = ((unsigned)v) << 16;
  return x.f;
}
static __device__ __forceinline__ float fsig(float x) {
  float e = __expf(-x);
  return __builtin_amdgcn_rcpf(1.f + e);
}
static __device__ __forceinline__ float ftanh(float x) {
  float e = __expf(2.f * x);
  return 1.f - 2.f * __builtin_amdgcn_rcpf(1.f + e);
}

// fp32 (rows,K) -> bf16 (rows,ldp), zero pad cols K..ldp
__global__ void cvt_pad(const float* __restrict__ src, u16* __restrict__ dst,
                        int rows, int K, int ldp) {
  int idx = blockIdx.x * blockDim.x + threadIdx.x;
  int tot = rows * ldp;
  if (idx >= tot) return;
  int c = idx % ldp; int r = idx / ldp;
  float v = (c < K) ? src[(size_t)r * K + c] : 0.f;
  dst[idx] = f2bf(v);
}

// o[j] = bi[j] + (j<512 ? bh[j] : 0)  (bake bhh_{r,z} into input-side bias)
__global__ void bias_comb(const float* __restrict__ bi, const float* __restrict__ bh,
                          float* __restrict__ o) {
  int j = blockIdx.x * blockDim.x + threadIdx.x;
  if (j >= G3) return;
  o[j] = bi[j] + (j < 512 ? bh[j] : 0.f);
}

// C = A @ B^T + bias; 2 row-tiles x 4 col-tiles per wave.
// M%32==0, N%64==0, K%32==0.
__global__ void gemm_bt24(const u16* __restrict__ A, const u16* __restrict__ B,
                          float* __restrict__ C, u16* __restrict__ Cbf,
                          const float* __restrict__ bias,
                          int M, int N, int K, int lda, int ldb, int ldc) {
  int gid = blockIdx.x * blockDim.x + threadIdx.x;
  int wid = gid >> 6, lane = gid & 63;
  int ntg = N >> 6;
  int total = (M >> 5) * ntg;
  if (wid >= total) return;
  int tm = wid / ntg, tg = wid - tm * ntg;
  int rbase = tm << 5, cbase = tg << 6;
  int m = lane & 15, quad = lane >> 4;
  const u16* ap0 = A + (size_t)(rbase + m) * lda + quad * 8;
  const u16* ap1 = ap0 + (size_t)16 * lda;
  const u16* bp0 = B + (size_t)(cbase + m) * ldb + quad * 8;
  f32x4 acc[2][4];
  #pragma unroll
  for (int r = 0; r < 2; ++r)
    #pragma unroll
    for (int c = 0; c < 4; ++c) acc[r][c] = (f32x4){0.f, 0.f, 0.f, 0.f};
  for (int k = 0; k < K; k += 32) {
    bf16x8 a0 = *(const bf16x8*)(ap0 + k);
    bf16x8 a1 = *(const bf16x8*)(ap1 + k);
    #pragma unroll
    for (int c = 0; c < 4; ++c) {
      bf16x8 bv = *(const bf16x8*)(bp0 + (size_t)c * 16 * ldb + k);
      acc[0][c] = __builtin_amdgcn_mfma_f32_16x16x32_bf16(a0, bv, acc[0][c], 0, 0, 0);
      acc[1][c] = __builtin_amdgcn_mfma_f32_16x16x32_bf16(a1, bv, acc[1][c], 0, 0, 0);
    }
  }
  #pragma unroll
  for (int c = 0; c < 4; ++c) {
    int col = cbase + c * 16 + m;
    float bv = bias ? bias[col] : 0.f;
    #pragma unroll
    for (int rt = 0; rt < 2; ++rt) {
      int orow = rbase + rt * 16 + quad * 4;
      #pragma unroll
      for (int i = 0; i < 4; ++i) {
        float v = acc[rt][c][i] + bv;
        if (Cbf) Cbf[(size_t)(orow + i) * ldc + col] = f2bf(v);
        else C[(size_t)(orow + i) * ldc + col] = v;
      }
    }
  }
}

// ---- Persistent key-GRU: 256 blocks x 512 threads, 80 rows/block ----
// Row space (20480): [0,5120) c-fwd, [5120,10240) r-fwd, then same bwd.
// T tables already include bif + bhf_{r,z}; bhf_n applied at n-gate.
__global__ __launch_bounds__(512, 2) void key_gru2(
    const u16* __restrict__ Whf, const u16* __restrict__ Whb,
    const float* __restrict__ nbf, const float* __restrict__ nbb,
    const u16* __restrict__ TF, const u16* __restrict__ TB,
    const int* __restrict__ keys_c, const int* __restrict__ keys_r,
    float* __restrict__ h_out) {
  __shared__ __align__(16) u16 hbf[80 * 256];   // 40 KB, chunk-swizzled
  __shared__ __align__(16) u16 giL[80 * 768];   // 120 KB, chunk-swizzled
  int b = blockIdx.x;
  int grp = b >> 6;
  int bwd = grp >> 1, isR = grp & 1;
  int seq0 = (b & 63) * 80;
  const u16* W = bwd ? Whb : Whf;
  const u16* T = bwd ? TB : TF;
  const int* keys = isR ? keys_r : keys_c;
  const float* nb = bwd ? nbb : nbf;

  int tid = threadIdx.x;
  int w = tid >> 6, lane = tid & 63, m = lane & 15, quad = lane >> 4;
  int c0 = w * 16 + m, c1 = (w + 8) * 16 + m;
  float nb0 = nb[512 + c0], nb1 = nb[512 + c1];

  // W fragment row pointers for this lane's 6 col-tiles
  const u16* bp[2][3];
  #pragma unroll
  for (int jg = 0; jg < 2; ++jg)
    #pragma unroll
    for (int g = 0; g < 3; ++g)
      bp[jg][g] = W + (size_t)((w + 8 * jg + 16 * g) * 16 + m) * 256 + quad * 8;

  for (int i = tid * 8; i < 80 * 256; i += 512 * 8)
    *(i32x4*)&hbf[i] = (i32x4){0, 0, 0, 0};
  float h[5][2][4];
  #pragma unroll
  for (int rt = 0; rt < 5; ++rt)
    #pragma unroll
    for (int jg = 0; jg < 2; ++jg)
      #pragma unroll
      for (int i = 0; i < 4; ++i) h[rt][jg][i] = 0.f;

  for (int step = 0; step < KK; ++step) {
    __syncthreads();   // prev update done; giL free; hbf current
    int tt = bwd ? (KK - 1 - step) : step;

    f32x4 acc[5][2][3];
    #pragma unroll
    for (int rt = 0; rt < 5; ++rt)
      #pragma unroll
      for (int jg = 0; jg < 2; ++jg)
        #pragma unroll
        for (int g = 0; g < 3; ++g) acc[rt][jg][g] = (f32x4){0.f, 0.f, 0.f, 0.f};

    i32x4 st[5];
    auto issue = [&](int g) {
      #pragma unroll
      for (int s = 0; s < 5; ++s) {
        int f = (g * 5 + s) * 512 + tid;
        int row = f / 96, ch = f - row * 96;
        int tok = keys[(seq0 + row) * KK + tt];
        st[s] = *(const i32x4*)(T + (size_t)tok * G3 + ch * 8);
      }
    };
    auto commit = [&](int g) {
      #pragma unroll
      for (int s = 0; s < 5; ++s) {
        int f = (g * 5 + s) * 512 + tid;
        int row = f / 96, ch = f - row * 96;
        *(i32x4*)&giL[row * G3 + ((ch ^ ((row >> 2) & 3)) * 8)] = st[s];
      }
    };
    auto chunk = [&](int k) {
      bf16x8 a[5];
      #pragma unroll
      for (int rt = 0; rt < 5; ++rt) {
        int row = rt * 16 + m;
        a[rt] = *(const bf16x8*)&hbf[row * 256 + (((quad + 4 * k) ^ (row & 31)) * 8)];
      }
      #pragma unroll
      for (int jg = 0; jg < 2; ++jg)
        #pragma unroll
        for (int g = 0; g < 3; ++g) {
          bf16x8 bv = *(const bf16x8*)(bp[jg][g] + k * 32);
          #pragma unroll
          for (int rt = 0; rt < 5; ++rt)
            acc[rt][jg][g] =
                __builtin_amdgcn_mfma_f32_16x16x32_bf16(a[rt], bv, acc[rt][jg][g], 0, 0, 0);
        }
    };

    issue(0);
    chunk(0); chunk(1); chunk(2);
    commit(0); issue(1);
    chunk(3); chunk(4); chunk(5);
    commit(1); issue(2);
    chunk(6); chunk(7);
    commit(2);

    __syncthreads();   // gh in regs, gi staged; hbf reads done

    #pragma unroll
    for (int rt = 0; rt < 5; ++rt) {
      #pragma unroll
      for (int i = 0; i < 4; ++i) {
        int row_l = rt * 16 + quad * 4 + i;
        int rb768 = row_l * G3;
        int rb256 = row_l * 256;
        int rsw = row_l & 31;
        #pragma unroll
        for (int jg = 0; jg < 2; ++jg) {
          int c = jg ? c1 : c0;
          int cc = c >> 3, lo = c & 7;
          float gr = bf2f(giL[rb768 + ((cc ^ quad) * 8) + lo]);
          float gz = bf2f(giL[rb768 + (((32 + cc) ^ quad) * 8) + lo]);
          float gn = bf2f(giL[rb768 + (((64 + cc) ^ quad) * 8) + lo]);
          float rr = fsig(gr + acc[rt][jg][0][i]);
          float zz = fsig(gz + acc[rt][jg][1][i]);
          float nn = ftanh(gn + rr * (acc[rt][jg][2][i] + (jg ? nb1 : nb0)));
          float hv = (1.f - zz) * nn + zz * h[rt][jg][i];
          h[rt][jg][i] = hv;
          hbf[rb256 + ((cc ^ rsw) * 8) + lo] = f2bf(hv);
        }
      }
    }
  }

  #pragma unroll
  for (int rt = 0; rt < 5; ++rt)
    #pragma unroll
    for (int i = 0; i < 4; ++i)
      #pragma unroll
      for (int jg = 0; jg < 2; ++jg)
        h_out[(size_t)(b * 80 + rt * 16 + quad * 4 + i) * 256 + (jg ? c1 : c0)] =
            h[rt][jg][i];
}

// Build concat inputs for the main GRU, bf16 padded.
__global__ void build_xe(const float* __restrict__ emb, const int* __restrict__ x1,
                         const int* __restrict__ x2, const float* __restrict__ hk,
                         u16* __restrict__ xe) {
  int idx = blockIdx.x * blockDim.x + threadIdx.x;
  if (idx >= NROW * EHP) return;
  int c = idx % EHP; int rr = idx / EHP;
  int isX2 = rr >= NSEQ;
  int seq = rr - (isX2 ? NSEQ : 0);
  float v;
  if (c < EE) {
    int tok = (isX2 ? x2 : x1)[seq];
    v = emb[(size_t)tok * EE + c];
  } else if (c < EE + HH) {
    int j = c - EE;
    int frow = (isX2 ? NSEQ : 0) + seq;
    v = hk[(size_t)frow * HH + j] + hk[(size_t)(NROW + frow) * HH + j];
  } else {
    v = 0.f;
  }
  xe[idx] = f2bf(v);
}

// ---- Persistent main GRU: 8 blocks x 256 threads, 160 steps internal ----
// Block rt owns rows [rt*16, rt*16+16); q=rt>>1: 0=x1f,1=x2f,2=x1b,3=x2b.
// Gf/Gb already include ebif + ebhf_{r,z}; ebh_n applied at n-gate.
__global__ __launch_bounds__(256, 1) void main_gru2(
    const u16* __restrict__ Wf, const u16* __restrict__ Wb,
    const float* __restrict__ nbf, const float* __restrict__ nbb,
    const float* __restrict__ Gf, const float* __restrict__ Gb,
    float* __restrict__ sc, u16* __restrict__ scbf,
    float* __restrict__ h_final) {
  __shared__ __align__(16) u16 hbf[16 * 256];
  int rt = blockIdx.x;
  int q = rt >> 1;
  int bwd = q >> 1, isX2 = q & 1;
  const u16* W = bwd ? Wb : Wf;
  const float* G = bwd ? Gb : Gf;
  const float* nb = bwd ? nbb : nbf;
  int tid = threadIdx.x, w = tid >> 6, lane = tid & 63, m = lane & 15, quad = lane >> 4;

  int cj[4]; float nbv[4];
  const u16* bp[4][3];
  #pragma unroll
  for (int jj = 0; jj < 4; ++jj) {
    cj[jj] = (w + 4 * jj) * 16 + m;
    nbv[jj] = nb[512 + cj[jj]];
    #pragma unroll
    for (int g = 0; g < 3; ++g)
      bp[jj][g] = W + (size_t)((w + 4 * jj + 16 * g) * 16 + m) * 256 + quad * 8;
  }

  for (int i = tid * 8; i < 16 * 256; i += 256 * 8)
    *(i32x4*)&hbf[i] = (i32x4){0, 0, 0, 0};
  float h[4][4];
  #pragma unroll
  for (int jj = 0; jj < 4; ++jj)
    #pragma unroll
    for (int i = 0; i < 4; ++i) h[jj][i] = 0.f;

  for (int step = 0; step < SS; ++step) {
    __syncthreads();
    int s = bwd ? (SS - 1 - step) : step;
    // prefetch gi (overlaps GEMM)
    float gi[4][4][3];
    #pragma unroll
    for (int i = 0; i < 4; ++i) {
      int bb = ((rt & 1) << 4) + quad * 4 + i;
      size_t girow = ((size_t)(isX2 * NSEQ + bb * SS + s)) * G3;
      #pragma unroll
      for (int jj = 0; jj < 4; ++jj)
        #pragma unroll
        for (int g = 0; g < 3; ++g)
          gi[jj][i][g] = G[girow + cj[jj] + 256 * g];
    }
    f32x4 acc[4][3];
    #pragma unroll
    for (int jj = 0; jj < 4; ++jj)
      #pragma unroll
      for (int g = 0; g < 3; ++g) acc[jj][g] = (f32x4){0.f, 0.f, 0.f, 0.f};
    #pragma unroll
    for (int k = 0; k < 8; ++k) {
      bf16x8 a = *(const bf16x8*)&hbf[m * 256 + (((quad + 4 * k) ^ m) * 8)];
      #pragma unroll
      for (int jj = 0; jj < 4; ++jj)
        #pragma unroll
        for (int g = 0; g < 3; ++g) {
          bf16x8 bv = *(const bf16x8*)(bp[jj][g] + k * 32);
          acc[jj][g] = __builtin_amdgcn_mfma_f32_16x16x32_bf16(a, bv, acc[jj][g], 0, 0, 0);
        }
    }
    __syncthreads();
    #pragma unroll
    for (int jj = 0; jj < 4; ++jj) {
      int c = cj[jj], cc = c >> 3, lo = c & 7;
      #pragma unroll
      for (int i = 0; i < 4; ++i) {
        int row_l = quad * 4 + i;
        float rr = fsig(gi[jj][i][0] + acc[jj][0][i]);
        float zz = fsig(gi[jj][i][1] + acc[jj][1][i]);
        float nn = ftanh(gi[jj][i][2] + rr * (acc[jj][2][i] + nbv[jj]));
        float hv = (1.f - zz) * nn + zz * h[jj][i];
        h[jj][i] = hv;
        hbf[row_l * 256 + ((cc ^ row_l) * 8) + lo] = f2bf(hv);
        if (!isX2) {
          int bb = ((rt & 1) << 4) + row_l;
          size_t o = (size_t)(bb * SS + s) * 512 + (bwd ? 256 : 0) + c;
          sc[o] = hv;
          scbf[o] = f2bf(hv);
        }
      }
    }
  }
  #pragma unroll
  for (int jj = 0; jj < 4; ++jj)
    #pragma unroll
    for (int i = 0; i < 4; ++i)
      h_final[(size_t)(rt * 16 + quad * 4 + i) * 256 + cj[jj]] = h[jj][i];
}

// r = concat(r1f, r1b) (+ bf16 copy)
__global__ void extract_r(const float* __restrict__ h, float* __restrict__ r,
                          u16* __restrict__ rbf) {
  int idx = blockIdx.x * blockDim.x + threadIdx.x;
  if (idx >= BB * 512) return;
  int bb = idx >> 9, j = idx & 511;
  int row = (j < 256) ? (32 + bb) : (96 + bb);
  float v = h[row * HH + (j & 255)];
  r[idx] = v;
  rbf[idx] = f2bf(v);
}

__global__ void energies_k(const float* __restrict__ a, const float* __restrict__ r,
                           float* __restrict__ e) {
  int gid = blockIdx.x * blockDim.x + threadIdx.x;
  int wid = gid >> 6, lane = gid & 63;
  if (wid >= NSEQ) return;
  int b = wid / SS;
  const float* ar = a + (size_t)wid * 512;
  const float* rr = r + (size_t)b * 512;
  float sum = 0.f;
  for (int i = lane; i < 512; i += 64) sum += ar[i] * rr[i];
  for (int off = 32; off > 0; off >>= 1) sum += __shfl_down(sum, off);
  if (lane == 0) e[wid] = sum;
}

__global__ void softmax_k(const float* __restrict__ e, const float* __restrict__ mask,
                          float* __restrict__ alpha) {
  __shared__ float red[256];
  int b = blockIdx.x, tid = threadIdx.x;
  float v = (tid < SS) ? e[b * SS + tid] : -1e30f;
  red[tid] = v; __syncthreads();
  for (int s = 128; s > 0; s >>= 1) { if (tid < s) red[tid] = fmaxf(red[tid], red[tid + s]); __syncthreads(); }
  float mx = red[0]; __syncthreads();
  float ex = (tid < SS) ? expf(v - mx) : 0.f;
  red[tid] = ex; __syncthreads();
  for (int s = 128; s > 0; s >>= 1) { if (tid < s) red[tid] += red[tid + s]; __syncthreads(); }
  float denom = red[0];
  if (tid < SS) alpha[b * SS + tid] = ex / denom * mask[b * SS + tid];
}

__global__ void cattn_k(const float* __restrict__ alpha, const float* __restrict__ sc,
                        float* __restrict__ c) {
  int b = blockIdx.x, d = threadIdx.x;
  float sum = 0.f;
  for (int s = 0; s < SS; ++s)
    sum += alpha[b * SS + s] * sc[(size_t)(b * SS + s) * 512 + d];
  c[b * 512 + d] = sum;
}

__global__ void final_dot(const float* __restrict__ c, const float* __restrict__ v,
                          const float* __restrict__ bsc, float* __restrict__ out) {
  int b = blockIdx.x, lane = threadIdx.x;
  float s = 0.f;
  for (int i = lane; i < 512; i += 64) s += c[b * 512 + i] * v[b * 512 + i];
  for (int off = 32; off > 0; off >>= 1) s += __shfl_down(s, off);
  if (lane == 0) out[b] = s + bsc[0];
}

extern "C" void kernel_launch(void* const* d_in, const int* in_sizes, int n_in,
                              void* d_out, int out_size, void* d_ws, size_t ws_size,
                              hipStream_t stream) {
  const int*   x1     = (const int*)d_in[0];
  const int*   x2     = (const int*)d_in[1];
  const int*   keys_c = (const int*)d_in[2];
  const int*   keys_r = (const int*)d_in[3];
  const float* x1mask = (const float*)d_in[4];
  const float* emb    = (const float*)d_in[5];
  const float* kWif   = (const float*)d_in[6];
  const float* kWhf   = (const float*)d_in[7];
  const float* kbif   = (const float*)d_in[8];
  const float* kbhf   = (const float*)d_in[9];
  const float* kWib   = (const float*)d_in[10];
  const float* kWhb   = (const float*)d_in[11];
  const float* kbib   = (const float*)d_in[12];
  const float* kbhb   = (const float*)d_in[13];
  const float* eWif   = (const float*)d_in[14];
  const float* eWhf   = (const float*)d_in[15];
  const float* ebif   = (const float*)d_in[16];
  const float* ebhf   = (const float*)d_in[17];
  const float* eWib   = (const float*)d_in[18];
  const float* eWhb   = (const float*)d_in[19];
  const float* ebib   = (const float*)d_in[20];
  const float* ebhb   = (const float*)d_in[21];
  const float* attnW  = (const float*)d_in[22];
  const float* attnb  = (const float*)d_in[23];
  const float* Mw     = (const float*)d_in[24];
  const float* bsc    = (const float*)d_in[25];
  float* out = (float*)d_out;

  char* base = (char*)d_ws;
  size_t off = 0;
  auto take = [&](size_t bytes) -> void* {
    void* p = base + off; off += (bytes + 255) & ~(size_t)255; return p;
  };

  // ---- shared (live whole launch) ----
  u16* kWif_bf = (u16*)take((size_t)G3 * EP * 2);
  u16* kWib_bf = (u16*)take((size_t)G3 * EP * 2);
  u16* kWhf_bf = (u16*)take((size_t)G3 * HH * 2);
  u16* kWhb_bf = (u16*)take((size_t)G3 * HH * 2);
  u16* eWif_bf = (u16*)take((size_t)G3 * EHP * 2);
  u16* eWib_bf = (u16*)take((size_t)G3 * EHP * 2);
  u16* eWhf_bf = (u16*)take((size_t)G3 * HH * 2);
  u16* eWhb_bf = (u16*)take((size_t)G3 * HH * 2);
  u16* attnW_bf = (u16*)take((size_t)512 * 512 * 2);
  u16* M_bf    = (u16*)take((size_t)512 * 512 * 2);
  u16* xe_bf   = (u16*)take((size_t)NROW * EHP * 2);
  float* cb_kf = (float*)take(G3 * 4);
  float* cb_kb = (float*)take(G3 * 4);
  float* cb_ef = (float*)take(G3 * 4);
  float* cb_eb = (float*)take(G3 * 4);

  size_t pbase = off;
  // ---- phase 1 (key GRU) ----
  u16*   emb_bf = (u16*)take((size_t)VV * EP * 2);
  u16*   TF     = (u16*)take((size_t)VV * G3 * 2);
  u16*   TB     = (u16*)take((size_t)VV * G3 * 2);
  float* h_key  = (float*)take((size_t)NKEY * HH * 4);

  // ---- phase 2 overlaps emb_bf/TF/TB (dead after key phase) ----
  off = pbase;
  float* Gf = (float*)take((size_t)NROW * G3 * 4);
  float* Gb = (float*)take((size_t)NROW * G3 * 4);
  float* h_main = (float*)take((size_t)128 * HH * 4);
  float* sc = (float*)take((size_t)NSEQ * 512 * 4);
  u16*   sc_bf = (u16*)take((size_t)NSEQ * 512 * 2);
  float* rvec = (float*)take((size_t)BB * 512 * 4);
  u16*   r_bf = (u16*)take((size_t)BB * 512 * 2);
  float* abuf = (float*)take((size_t)NSEQ * 512 * 4);
  float* energ = (float*)take((size_t)BB * SS * 4);
  float* alpha = (float*)take((size_t)BB * SS * 4);
  float* c_attn = (float*)take((size_t)BB * 512 * 4);
  float* vbuf = (float*)take((size_t)BB * 512 * 4);

  auto cvt = [&](const float* s, u16* d, int rows, int K, int ldp) {
    int tot = rows * ldp;
    cvt_pad<<<(tot + 255) / 256, 256, 0, stream>>>(s, d, rows, K, ldp);
  };
  auto gemm = [&](const u16* A, const u16* B, float* C, u16* Cbf, const float* bias,
                  int M, int N, int K, int lda, int ldb, int ldc) {
    long long waves = (long long)(M >> 5) * (N >> 6);
    int blocks = (int)((waves * 64 + 255) / 256);
    gemm_bt24<<<blocks, 256, 0, stream>>>(A, B, C, Cbf, bias, M, N, K, lda, ldb, ldc);
  };

  cvt(emb, emb_bf, VV, EE, EP);
  cvt(kWif, kWif_bf, G3, EE, EP);
  cvt(kWib, kWib_bf, G3, EE, EP);
  cvt(kWhf, kWhf_bf, G3, HH, HH);
  cvt(kWhb, kWhb_bf, G3, HH, HH);
  cvt(eWif, eWif_bf, G3, 556, EHP);
  cvt(eWib, eWib_bf, G3, 556, EHP);
  cvt(eWhf, eWhf_bf, G3, HH, HH);
  cvt(eWhb, eWhb_bf, G3, HH, HH);
  cvt(attnW, attnW_bf, 512, 512, 512);
  cvt(Mw, M_bf, 512, 512, 512);
  bias_comb<<<3, 256, 0, stream>>>(kbif, kbhf, cb_kf);
  bias_comb<<<3, 256, 0, stream>>>(kbib, kbhb, cb_kb);
  bias_comb<<<3, 256, 0, stream>>>(ebif, ebhf, cb_ef);
  bias_comb<<<3, 256, 0, stream>>>(ebib, ebhb, cb_eb);

  // Key tables: T[v] = emb[v]@Wih.T + bif + bhf_{r,z}
  gemm(emb_bf, kWif_bf, nullptr, TF, cb_kf, VV, G3, EP, EP, EP, G3);
  gemm(emb_bf, kWib_bf, nullptr, TB, cb_kb, VV, G3, EP, EP, EP, G3);

  // Key GRU: one persistent launch
  key_gru2<<<256, 512, 0, stream>>>(kWhf_bf, kWhb_bf, kbhf, kbhb,
                                    TF, TB, keys_c, keys_r, h_key);

  build_xe<<<(NROW * EHP + 255) / 256, 256, 0, stream>>>(emb, x1, x2, h_key, xe_bf);

  gemm(xe_bf, eWif_bf, Gf, nullptr, cb_ef, NROW, G3, EHP, EHP, EHP, G3);
  gemm(xe_bf, eWib_bf, Gb, nullptr, cb_eb, NROW, G3, EHP, EHP, EHP, G3);

  // Main GRU: one persistent launch, 160 steps
  main_gru2<<<8, 256, 0, stream>>>(eWhf_bf, eWhb_bf, ebhf, ebhb,
                                   Gf, Gb, sc, sc_bf, h_main);

  extract_r<<<(BB * 512 + 255) / 256, 256, 0, stream>>>(h_main, rvec, r_bf);

  gemm(sc_bf, attnW_bf, abuf, nullptr, attnb, NSEQ, 512, 512, 512, 512, 512);
  energies_k<<<(NSEQ * 64 + 255) / 256, 256, 0, stream>>>(abuf, rvec, energ);
  softmax_k<<<BB, 256, 0, stream>>>(energ, x1mask, alpha);
  cattn_k<<<BB, 512, 0, stream>>>(alpha, sc, c_attn);
  gemm(r_bf, M_bf, vbuf, nullptr, nullptr, BB, 512, 512, 512, 512, 512);
  final_dot<<<BB, 64, 0, stream>>>(c_attn, vbuf, bsc, out);
}

// Round 4
// 4591.774 us; speedup vs baseline: 1.7690x; 1.0823x over previous
//
#include <hip/hip_runtime.h>
#include <hip/hip_bf16.h>

#define BB 32
#define SS 160
#define KK 44
#define EE 300
#define HH 256
#define VV 32000
#define G3 768
#define EHP 576
#define EP  320
#define NSEQ 5120
#define NROW 10240
#define NKEY 20480

typedef unsigned short u16;
typedef __attribute__((ext_vector_type(8))) short bf16x8;
typedef __attribute__((ext_vector_type(4))) float f32x4;
typedef __attribute__((ext_vector_type(4))) int i32x4;

static __device__ __forceinline__ u16 f2bf(float f) {
  union { float f; unsigned u; } x; x.f = f;
  unsigned u = x.u;
  unsigned r = (u + 0x7fffu + ((u >> 16) & 1u)) >> 16;
  return (u16)r;
}
static __device__ __forceinline__ float bf2f(u16 v) {
  union { unsigned u; float f; } x; x.u = ((unsigned)v) << 16;
  return x.f;
}
static __device__ __forceinline__ float fsig(float x) {
  float e = __expf(-x);
  return __builtin_amdgcn_rcpf(1.f + e);
}
static __device__ __forceinline__ float ftanh(float x) {
  float e = __expf(2.f * x);
  return 1.f - 2.f * __builtin_amdgcn_rcpf(1.f + e);
}

// fp32 (rows,K) -> bf16 (rows,ldp), zero pad cols K..ldp
__global__ void cvt_pad(const float* __restrict__ src, u16* __restrict__ dst,
                        int rows, int K, int ldp) {
  int idx = blockIdx.x * blockDim.x + threadIdx.x;
  int tot = rows * ldp;
  if (idx >= tot) return;
  int c = idx % ldp; int r = idx / ldp;
  float v = (c < K) ? src[(size_t)r * K + c] : 0.f;
  dst[idx] = f2bf(v);
}

// o[j] = bi[j] + (j<512 ? bh[j] : 0)
__global__ void bias_comb(const float* __restrict__ bi, const float* __restrict__ bh,
                          float* __restrict__ o) {
  int j = blockIdx.x * blockDim.x + threadIdx.x;
  if (j >= G3) return;
  o[j] = bi[j] + (j < 512 ? bh[j] : 0.f);
}

// C = A @ B^T + bias; 2 row-tiles x 4 col-tiles per wave.
__global__ void gemm_bt24(const u16* __restrict__ A, const u16* __restrict__ B,
                          float* __restrict__ C, u16* __restrict__ Cbf,
                          const float* __restrict__ bias,
                          int M, int N, int K, int lda, int ldb, int ldc) {
  int gid = blockIdx.x * blockDim.x + threadIdx.x;
  int wid = gid >> 6, lane = gid & 63;
  int ntg = N >> 6;
  int total = (M >> 5) * ntg;
  if (wid >= total) return;
  int tm = wid / ntg, tg = wid - tm * ntg;
  int rbase = tm << 5, cbase = tg << 6;
  int m = lane & 15, quad = lane >> 4;
  const u16* ap0 = A + (size_t)(rbase + m) * lda + quad * 8;
  const u16* ap1 = ap0 + (size_t)16 * lda;
  const u16* bp0 = B + (size_t)(cbase + m) * ldb + quad * 8;
  f32x4 acc[2][4];
  #pragma unroll
  for (int r = 0; r < 2; ++r)
    #pragma unroll
    for (int c = 0; c < 4; ++c) acc[r][c] = (f32x4){0.f, 0.f, 0.f, 0.f};
  for (int k = 0; k < K; k += 32) {
    bf16x8 a0 = *(const bf16x8*)(ap0 + k);
    bf16x8 a1 = *(const bf16x8*)(ap1 + k);
    #pragma unroll
    for (int c = 0; c < 4; ++c) {
      bf16x8 bv = *(const bf16x8*)(bp0 + (size_t)c * 16 * ldb + k);
      acc[0][c] = __builtin_amdgcn_mfma_f32_16x16x32_bf16(a0, bv, acc[0][c], 0, 0, 0);
      acc[1][c] = __builtin_amdgcn_mfma_f32_16x16x32_bf16(a1, bv, acc[1][c], 0, 0, 0);
    }
  }
  #pragma unroll
  for (int c = 0; c < 4; ++c) {
    int col = cbase + c * 16 + m;
    float bv = bias ? bias[col] : 0.f;
    #pragma unroll
    for (int rt = 0; rt < 2; ++rt) {
      int orow = rbase + rt * 16 + quad * 4;
      #pragma unroll
      for (int i = 0; i < 4; ++i) {
        float v = acc[rt][c][i] + bv;
        if (Cbf) Cbf[(size_t)(orow + i) * ldc + col] = f2bf(v);
        else C[(size_t)(orow + i) * ldc + col] = v;
      }
    }
  }
}

// ---- Persistent key-GRU: 256 blocks x 512 threads, 80 rows/block ----
// T gathers use non-temporal loads (zero reuse) so Whh stays L2-resident.
__global__ __launch_bounds__(512, 2) void key_gru2(
    const u16* __restrict__ Whf, const u16* __restrict__ Whb,
    const float* __restrict__ nbf, const float* __restrict__ nbb,
    const u16* __restrict__ TF, const u16* __restrict__ TB,
    const int* __restrict__ keys_c, const int* __restrict__ keys_r,
    float* __restrict__ h_out) {
  __shared__ __align__(16) u16 hbf[80 * 256];   // 40 KB
  __shared__ __align__(16) u16 giL[80 * 768];   // 120 KB
  int b = blockIdx.x;
  int grp = b >> 6;
  int bwd = grp >> 1, isR = grp & 1;
  int seq0 = (b & 63) * 80;
  const u16* W = bwd ? Whb : Whf;
  const u16* T = bwd ? TB : TF;
  const int* keys = isR ? keys_r : keys_c;
  const float* nb = bwd ? nbb : nbf;

  int tid = threadIdx.x;
  int w = tid >> 6, lane = tid & 63, m = lane & 15, quad = lane >> 4;
  int c0 = w * 16 + m, c1 = (w + 8) * 16 + m;
  float nb0 = nb[512 + c0], nb1 = nb[512 + c1];

  const u16* bp[2][3];
  #pragma unroll
  for (int jg = 0; jg < 2; ++jg)
    #pragma unroll
    for (int g = 0; g < 3; ++g)
      bp[jg][g] = W + (size_t)((w + 8 * jg + 16 * g) * 16 + m) * 256 + quad * 8;

  for (int i = tid * 8; i < 80 * 256; i += 512 * 8)
    *(i32x4*)&hbf[i] = (i32x4){0, 0, 0, 0};
  float h[5][2][4];
  #pragma unroll
  for (int rt = 0; rt < 5; ++rt)
    #pragma unroll
    for (int jg = 0; jg < 2; ++jg)
      #pragma unroll
      for (int i = 0; i < 4; ++i) h[rt][jg][i] = 0.f;

  for (int step = 0; step < KK; ++step) {
    __syncthreads();
    int tt = bwd ? (KK - 1 - step) : step;

    // Prefetch the 15 row-tokens this thread's fragments need (independent loads)
    int toks[15];
    #pragma unroll
    for (int f15 = 0; f15 < 15; ++f15) {
      int f = f15 * 512 + tid;
      int row = f / 96;
      toks[f15] = keys[(seq0 + row) * KK + tt];
    }

    f32x4 acc[5][2][3];
    #pragma unroll
    for (int rt = 0; rt < 5; ++rt)
      #pragma unroll
      for (int jg = 0; jg < 2; ++jg)
        #pragma unroll
        for (int g = 0; g < 3; ++g) acc[rt][jg][g] = (f32x4){0.f, 0.f, 0.f, 0.f};

    i32x4 st[5];
    auto issue = [&](int g) {
      #pragma unroll
      for (int s = 0; s < 5; ++s) {
        int f15 = g * 5 + s;
        int f = f15 * 512 + tid;
        int row = f / 96, ch = f - row * 96;
        st[s] = __builtin_nontemporal_load(
            (const i32x4*)(T + (size_t)toks[f15] * G3 + ch * 8));
      }
    };
    auto commit = [&](int g) {
      #pragma unroll
      for (int s = 0; s < 5; ++s) {
        int f = (g * 5 + s) * 512 + tid;
        int row = f / 96, ch = f - row * 96;
        *(i32x4*)&giL[row * G3 + ((ch ^ ((row >> 2) & 3)) * 8)] = st[s];
      }
    };
    auto chunk = [&](int k) {
      bf16x8 a[5];
      #pragma unroll
      for (int rt = 0; rt < 5; ++rt) {
        int row = rt * 16 + m;
        a[rt] = *(const bf16x8*)&hbf[row * 256 + (((quad + 4 * k) ^ (row & 31)) * 8)];
      }
      #pragma unroll
      for (int jg = 0; jg < 2; ++jg)
        #pragma unroll
        for (int g = 0; g < 3; ++g) {
          bf16x8 bv = *(const bf16x8*)(bp[jg][g] + k * 32);
          #pragma unroll
          for (int rt = 0; rt < 5; ++rt)
            acc[rt][jg][g] =
                __builtin_amdgcn_mfma_f32_16x16x32_bf16(a[rt], bv, acc[rt][jg][g], 0, 0, 0);
        }
    };

    issue(0);
    chunk(0); chunk(1); chunk(2);
    commit(0); issue(1);
    chunk(3); chunk(4); chunk(5);
    commit(1); issue(2);
    chunk(6); chunk(7);
    commit(2);

    __syncthreads();

    #pragma unroll
    for (int rt = 0; rt < 5; ++rt) {
      #pragma unroll
      for (int i = 0; i < 4; ++i) {
        int row_l = rt * 16 + quad * 4 + i;
        int rb768 = row_l * G3;
        int rb256 = row_l * 256;
        int rsw = row_l & 31;
        #pragma unroll
        for (int jg = 0; jg < 2; ++jg) {
          int c = jg ? c1 : c0;
          int cc = c >> 3, lo = c & 7;
          float gr = bf2f(giL[rb768 + ((cc ^ quad) * 8) + lo]);
          float gz = bf2f(giL[rb768 + (((32 + cc) ^ quad) * 8) + lo]);
          float gn = bf2f(giL[rb768 + (((64 + cc) ^ quad) * 8) + lo]);
          float rr = fsig(gr + acc[rt][jg][0][i]);
          float zz = fsig(gz + acc[rt][jg][1][i]);
          float nn = ftanh(gn + rr * (acc[rt][jg][2][i] + (jg ? nb1 : nb0)));
          float hv = (1.f - zz) * nn + zz * h[rt][jg][i];
          h[rt][jg][i] = hv;
          hbf[rb256 + ((cc ^ rsw) * 8) + lo] = f2bf(hv);
        }
      }
    }
  }

  // Coalesced fp32 epilogue: stage h through giL (dead now), then dwordx4 stores
  __syncthreads();
  float* hstage = (float*)giL;  // 80*256 floats = 80 KB
  #pragma unroll
  for (int rt = 0; rt < 5; ++rt)
    #pragma unroll
    for (int i = 0; i < 4; ++i)
      #pragma unroll
      for (int jg = 0; jg < 2; ++jg)
        hstage[(rt * 16 + quad * 4 + i) * 256 + (jg ? c1 : c0)] = h[rt][jg][i];
  __syncthreads();
  for (int i = tid * 4; i < 80 * 256; i += 512 * 4)
    *(f32x4*)&h_out[(size_t)b * 80 * 256 + i] = *(const f32x4*)&hstage[i];
}

// Build concat inputs for the main GRU, bf16 padded.
__global__ void build_xe(const float* __restrict__ emb, const int* __restrict__ x1,
                         const int* __restrict__ x2, const float* __restrict__ hk,
                         u16* __restrict__ xe) {
  int idx = blockIdx.x * blockDim.x + threadIdx.x;
  if (idx >= NROW * EHP) return;
  int c = idx % EHP; int rr = idx / EHP;
  int isX2 = rr >= NSEQ;
  int seq = rr - (isX2 ? NSEQ : 0);
  float v;
  if (c < EE) {
    int tok = (isX2 ? x2 : x1)[seq];
    v = emb[(size_t)tok * EE + c];
  } else if (c < EE + HH) {
    int j = c - EE;
    int frow = (isX2 ? NSEQ : 0) + seq;
    v = hk[(size_t)frow * HH + j] + hk[(size_t)(NROW + frow) * HH + j];
  } else {
    v = 0.f;
  }
  xe[idx] = f2bf(v);
}

// ---- Persistent main GRU: 8 blocks x 256 threads, 160 steps internal ----
__global__ __launch_bounds__(256, 1) void main_gru2(
    const u16* __restrict__ Wf, const u16* __restrict__ Wb,
    const float* __restrict__ nbf, const float* __restrict__ nbb,
    const float* __restrict__ Gf, const float* __restrict__ Gb,
    float* __restrict__ sc, u16* __restrict__ scbf,
    float* __restrict__ h_final) {
  __shared__ __align__(16) u16 hbf[16 * 256];
  int rt = blockIdx.x;
  int q = rt >> 1;
  int bwd = q >> 1, isX2 = q & 1;
  const u16* W = bwd ? Wb : Wf;
  const float* G = bwd ? Gb : Gf;
  const float* nb = bwd ? nbb : nbf;
  int tid = threadIdx.x, w = tid >> 6, lane = tid & 63, m = lane & 15, quad = lane >> 4;

  int cj[4]; float nbv[4];
  const u16* bp[4][3];
  #pragma unroll
  for (int jj = 0; jj < 4; ++jj) {
    cj[jj] = (w + 4 * jj) * 16 + m;
    nbv[jj] = nb[512 + cj[jj]];
    #pragma unroll
    for (int g = 0; g < 3; ++g)
      bp[jj][g] = W + (size_t)((w + 4 * jj + 16 * g) * 16 + m) * 256 + quad * 8;
  }

  for (int i = tid * 8; i < 16 * 256; i += 256 * 8)
    *(i32x4*)&hbf[i] = (i32x4){0, 0, 0, 0};
  float h[4][4];
  #pragma unroll
  for (int jj = 0; jj < 4; ++jj)
    #pragma unroll
    for (int i = 0; i < 4; ++i) h[jj][i] = 0.f;

  for (int step = 0; step < SS; ++step) {
    __syncthreads();
    int s = bwd ? (SS - 1 - step) : step;
    float gi[4][4][3];
    #pragma unroll
    for (int i = 0; i < 4; ++i) {
      int bb = ((rt & 1) << 4) + quad * 4 + i;
      size_t girow = ((size_t)(isX2 * NSEQ + bb * SS + s)) * G3;
      #pragma unroll
      for (int jj = 0; jj < 4; ++jj)
        #pragma unroll
        for (int g = 0; g < 3; ++g)
          gi[jj][i][g] = G[girow + cj[jj] + 256 * g];
    }
    f32x4 acc[4][3];
    #pragma unroll
    for (int jj = 0; jj < 4; ++jj)
      #pragma unroll
      for (int g = 0; g < 3; ++g) acc[jj][g] = (f32x4){0.f, 0.f, 0.f, 0.f};
    #pragma unroll
    for (int k = 0; k < 8; ++k) {
      bf16x8 a = *(const bf16x8*)&hbf[m * 256 + (((quad + 4 * k) ^ m) * 8)];
      #pragma unroll
      for (int jj = 0; jj < 4; ++jj)
        #pragma unroll
        for (int g = 0; g < 3; ++g) {
          bf16x8 bv = *(const bf16x8*)(bp[jj][g] + k * 32);
          acc[jj][g] = __builtin_amdgcn_mfma_f32_16x16x32_bf16(a, bv, acc[jj][g], 0, 0, 0);
        }
    }
    __syncthreads();
    #pragma unroll
    for (int jj = 0; jj < 4; ++jj) {
      int c = cj[jj], cc = c >> 3, lo = c & 7;
      #pragma unroll
      for (int i = 0; i < 4; ++i) {
        int row_l = quad * 4 + i;
        float rr = fsig(gi[jj][i][0] + acc[jj][0][i]);
        float zz = fsig(gi[jj][i][1] + acc[jj][1][i]);
        float nn = ftanh(gi[jj][i][2] + rr * (acc[jj][2][i] + nbv[jj]));
        float hv = (1.f - zz) * nn + zz * h[jj][i];
        h[jj][i] = hv;
        hbf[row_l * 256 + ((cc ^ row_l) * 8) + lo] = f2bf(hv);
        if (!isX2) {
          int bb = ((rt & 1) << 4) + row_l;
          size_t o = (size_t)(bb * SS + s) * 512 + (bwd ? 256 : 0) + c;
          sc[o] = hv;
          scbf[o] = f2bf(hv);
        }
      }
    }
  }
  #pragma unroll
  for (int jj = 0; jj < 4; ++jj)
    #pragma unroll
    for (int i = 0; i < 4; ++i)
      h_final[(size_t)(rt * 16 + quad * 4 + i) * 256 + cj[jj]] = h[jj][i];
}

// r = concat(r1f, r1b) (+ bf16 copy)
__global__ void extract_r(const float* __restrict__ h, float* __restrict__ r,
                          u16* __restrict__ rbf) {
  int idx = blockIdx.x * blockDim.x + threadIdx.x;
  if (idx >= BB * 512) return;
  int bb = idx >> 9, j = idx & 511;
  int row = (j < 256) ? (32 + bb) : (96 + bb);
  float v = h[row * HH + (j & 255)];
  r[idx] = v;
  rbf[idx] = f2bf(v);
}

__global__ void energies_k(const float* __restrict__ a, const float* __restrict__ r,
                           float* __restrict__ e) {
  int gid = blockIdx.x * blockDim.x + threadIdx.x;
  int wid = gid >> 6, lane = gid & 63;
  if (wid >= NSEQ) return;
  int b = wid / SS;
  const float* ar = a + (size_t)wid * 512;
  const float* rr = r + (size_t)b * 512;
  float sum = 0.f;
  for (int i = lane; i < 512; i += 64) sum += ar[i] * rr[i];
  for (int off = 32; off > 0; off >>= 1) sum += __shfl_down(sum, off);
  if (lane == 0) e[wid] = sum;
}

__global__ void softmax_k(const float* __restrict__ e, const float* __restrict__ mask,
                          float* __restrict__ alpha) {
  __shared__ float red[256];
  int b = blockIdx.x, tid = threadIdx.x;
  float v = (tid < SS) ? e[b * SS + tid] : -1e30f;
  red[tid] = v; __syncthreads();
  for (int s = 128; s > 0; s >>= 1) { if (tid < s) red[tid] = fmaxf(red[tid], red[tid + s]); __syncthreads(); }
  float mx = red[0]; __syncthreads();
  float ex = (tid < SS) ? expf(v - mx) : 0.f;
  red[tid] = ex; __syncthreads();
  for (int s = 128; s > 0; s >>= 1) { if (tid < s) red[tid] += red[tid + s]; __syncthreads(); }
  float denom = red[0];
  if (tid < SS) alpha[b * SS + tid] = ex / denom * mask[b * SS + tid];
}

__global__ void cattn_k(const float* __restrict__ alpha, const float* __restrict__ sc,
                        float* __restrict__ c) {
  int b = blockIdx.x, d = threadIdx.x;
  float sum = 0.f;
  for (int s = 0; s < SS; ++s)
    sum += alpha[b * SS + s] * sc[(size_t)(b * SS + s) * 512 + d];
  c[b * 512 + d] = sum;
}

__global__ void final_dot(const float* __restrict__ c, const float* __restrict__ v,
                          const float* __restrict__ bsc, float* __restrict__ out) {
  int b = blockIdx.x, lane = threadIdx.x;
  float s = 0.f;
  for (int i = lane; i < 512; i += 64) s += c[b * 512 + i] * v[b * 512 + i];
  for (int off = 32; off > 0; off >>= 1) s += __shfl_down(s, off);
  if (lane == 0) out[b] = s + bsc[0];
}

extern "C" void kernel_launch(void* const* d_in, const int* in_sizes, int n_in,
                              void* d_out, int out_size, void* d_ws, size_t ws_size,
                              hipStream_t stream) {
  const int*   x1     = (const int*)d_in[0];
  const int*   x2     = (const int*)d_in[1];
  const int*   keys_c = (const int*)d_in[2];
  const int*   keys_r = (const int*)d_in[3];
  const float* x1mask = (const float*)d_in[4];
  const float* emb    = (const float*)d_in[5];
  const float* kWif   = (const float*)d_in[6];
  const float* kWhf   = (const float*)d_in[7];
  const float* kbif   = (const float*)d_in[8];
  const float* kbhf   = (const float*)d_in[9];
  const float* kWib   = (const float*)d_in[10];
  const float* kWhb   = (const float*)d_in[11];
  const float* kbib   = (const float*)d_in[12];
  const float* kbhb   = (const float*)d_in[13];
  const float* eWif   = (const float*)d_in[14];
  const float* eWhf   = (const float*)d_in[15];
  const float* ebif   = (const float*)d_in[16];
  const float* ebhf   = (const float*)d_in[17];
  const float* eWib   = (const float*)d_in[18];
  const float* eWhb   = (const float*)d_in[19];
  const float* ebib   = (const float*)d_in[20];
  const float* ebhb   = (const float*)d_in[21];
  const float* attnW  = (const float*)d_in[22];
  const float* attnb  = (const float*)d_in[23];
  const float* Mw     = (const float*)d_in[24];
  const float* bsc    = (const float*)d_in[25];
  float* out = (float*)d_out;

  char* base = (char*)d_ws;
  size_t off = 0;
  auto take = [&](size_t bytes) -> void* {
    void* p = base + off; off += (bytes + 255) & ~(size_t)255; return p;
  };

  u16* kWif_bf = (u16*)take((size_t)G3 * EP * 2);
  u16* kWib_bf = (u16*)take((size_t)G3 * EP * 2);
  u16* kWhf_bf = (u16*)take((size_t)G3 * HH * 2);
  u16* kWhb_bf = (u16*)take((size_t)G3 * HH * 2);
  u16* eWif_bf = (u16*)take((size_t)G3 * EHP * 2);
  u16* eWib_bf = (u16*)take((size_t)G3 * EHP * 2);
  u16* eWhf_bf = (u16*)take((size_t)G3 * HH * 2);
  u16* eWhb_bf = (u16*)take((size_t)G3 * HH * 2);
  u16* attnW_bf = (u16*)take((size_t)512 * 512 * 2);
  u16* M_bf    = (u16*)take((size_t)512 * 512 * 2);
  u16* xe_bf   = (u16*)take((size_t)NROW * EHP * 2);
  float* cb_kf = (float*)take(G3 * 4);
  float* cb_kb = (float*)take(G3 * 4);
  float* cb_ef = (float*)take(G3 * 4);
  float* cb_eb = (float*)take(G3 * 4);

  size_t pbase = off;
  u16*   emb_bf = (u16*)take((size_t)VV * EP * 2);
  u16*   TF     = (u16*)take((size_t)VV * G3 * 2);
  u16*   TB     = (u16*)take((size_t)VV * G3 * 2);
  float* h_key  = (float*)take((size_t)NKEY * HH * 4);

  off = pbase;
  float* Gf = (float*)take((size_t)NROW * G3 * 4);
  float* Gb = (float*)take((size_t)NROW * G3 * 4);
  float* h_main = (float*)take((size_t)128 * HH * 4);
  float* sc = (float*)take((size_t)NSEQ * 512 * 4);
  u16*   sc_bf = (u16*)take((size_t)NSEQ * 512 * 2);
  float* rvec = (float*)take((size_t)BB * 512 * 4);
  u16*   r_bf = (u16*)take((size_t)BB * 512 * 2);
  float* abuf = (float*)take((size_t)NSEQ * 512 * 4);
  float* energ = (float*)take((size_t)BB * SS * 4);
  float* alpha = (float*)take((size_t)BB * SS * 4);
  float* c_attn = (float*)take((size_t)BB * 512 * 4);
  float* vbuf = (float*)take((size_t)BB * 512 * 4);

  auto cvt = [&](const float* s, u16* d, int rows, int K, int ldp) {
    int tot = rows * ldp;
    cvt_pad<<<(tot + 255) / 256, 256, 0, stream>>>(s, d, rows, K, ldp);
  };
  auto gemm = [&](const u16* A, const u16* B, float* C, u16* Cbf, const float* bias,
                  int M, int N, int K, int lda, int ldb, int ldc) {
    long long waves = (long long)(M >> 5) * (N >> 6);
    int blocks = (int)((waves * 64 + 255) / 256);
    gemm_bt24<<<blocks, 256, 0, stream>>>(A, B, C, Cbf, bias, M, N, K, lda, ldb, ldc);
  };

  cvt(emb, emb_bf, VV, EE, EP);
  cvt(kWif, kWif_bf, G3, EE, EP);
  cvt(kWib, kWib_bf, G3, EE, EP);
  cvt(kWhf, kWhf_bf, G3, HH, HH);
  cvt(kWhb, kWhb_bf, G3, HH, HH);
  cvt(eWif, eWif_bf, G3, 556, EHP);
  cvt(eWib, eWib_bf, G3, 556, EHP);
  cvt(eWhf, eWhf_bf, G3, HH, HH);
  cvt(eWhb, eWhb_bf, G3, HH, HH);
  cvt(attnW, attnW_bf, 512, 512, 512);
  cvt(Mw, M_bf, 512, 512, 512);
  bias_comb<<<3, 256, 0, stream>>>(kbif, kbhf, cb_kf);
  bias_comb<<<3, 256, 0, stream>>>(kbib, kbhb, cb_kb);
  bias_comb<<<3, 256, 0, stream>>>(ebif, ebhf, cb_ef);
  bias_comb<<<3, 256, 0, stream>>>(ebib, ebhb, cb_eb);

  gemm(emb_bf, kWif_bf, nullptr, TF, cb_kf, VV, G3, EP, EP, EP, G3);
  gemm(emb_bf, kWib_bf, nullptr, TB, cb_kb, VV, G3, EP, EP, EP, G3);

  key_gru2<<<256, 512, 0, stream>>>(kWhf_bf, kWhb_bf, kbhf, kbhb,
                                    TF, TB, keys_c, keys_r, h_key);

  build_xe<<<(NROW * EHP + 255) / 256, 256, 0, stream>>>(emb, x1, x2, h_key, xe_bf);

  gemm(xe_bf, eWif_bf, Gf, nullptr, cb_ef, NROW, G3, EHP, EHP, EHP, G3);
  gemm(xe_bf, eWib_bf, Gb, nullptr, cb_eb, NROW, G3, EHP, EHP, EHP, G3);

  main_gru2<<<8, 256, 0, stream>>>(eWhf_bf, eWhb_bf, ebhf, ebhb,
                                   Gf, Gb, sc, sc_bf, h_main);

  extract_r<<<(BB * 512 + 255) / 256, 256, 0, stream>>>(h_main, rvec, r_bf);

  gemm(sc_bf, attnW_bf, abuf, nullptr, attnb, NSEQ, 512, 512, 512, 512, 512);
  energies_k<<<(NSEQ * 64 + 255) / 256, 256, 0, stream>>>(abuf, rvec, energ);
  softmax_k<<<BB, 256, 0, stream>>>(energ, x1mask, alpha);
  cattn_k<<<BB, 512, 0, stream>>>(alpha, sc, c_attn);
  gemm(r_bf, M_bf, vbuf, nullptr, nullptr, BB, 512, 512, 512, 512, 512);
  final_dot<<<BB, 64, 0, stream>>>(c_attn, vbuf, bsc, out);
}